// Round 12
// baseline (4433.777 us; speedup 1.0000x reference)
//
#include <hip/hip_runtime.h>

typedef short bf16x8 __attribute__((ext_vector_type(8)));
typedef float f32x4 __attribute__((ext_vector_type(4)));
typedef unsigned int u32;
typedef u32 u32x4 __attribute__((ext_vector_type(4)));
typedef unsigned short u16;
typedef unsigned long long u64;

static __device__ __forceinline__ unsigned short f2bf(float f) {
    unsigned int u = __float_as_uint(f);
    unsigned int r = (u + 0x7fffu + ((u >> 16) & 1u)) >> 16;
    return (unsigned short)r;
}
static __device__ __forceinline__ float sigmoidf_(float x) {
    return 1.0f / (1.0f + __expf(-x));
}
static __device__ __forceinline__ float tanhf_(float x) {
    return 2.0f / (1.0f + __expf(-2.0f * x)) - 1.0f;
}

// truncation-split packing: fp32 -> (hi bf16, lo bf16)
static __device__ __forceinline__ u32 pkhi(float a, float b) {
    return (__float_as_uint(a) >> 16) | (__float_as_uint(b) & 0xffff0000u);
}
static __device__ __forceinline__ u32 pklo(float a, float b) {
    float la = a - __uint_as_float(__float_as_uint(a) & 0xffff0000u);
    float lb = b - __uint_as_float(__float_as_uint(b) & 0xffff0000u);
    return (__float_as_uint(la) >> 16) | (__float_as_uint(lb) & 0xffff0000u);
}
static __device__ __forceinline__ bf16x8 mkfrag(u32 a, u32 b, u32 c, u32 d) {
    u32x4 v = {a, b, c, d};
    return __builtin_bit_cast(bf16x8, v);
}

// ---- sc1 coherent activation access (fence-free scheme, proven R5+) ----
static __device__ __forceinline__ bf16x8 ldA(const u16* p) {
    u64 a = __hip_atomic_load((const u64*)p, __ATOMIC_RELAXED, __HIP_MEMORY_SCOPE_AGENT);
    u64 b = __hip_atomic_load((const u64*)(p + 4), __ATOMIC_RELAXED, __HIP_MEMORY_SCOPE_AGENT);
    union { u64 q[2]; bf16x8 v; } u;
    u.q[0] = a; u.q[1] = b;
    return u.v;
}
static __device__ __forceinline__ float ldc4(const float* p) {
    return __hip_atomic_load(p, __ATOMIC_RELAXED, __HIP_MEMORY_SCOPE_AGENT);
}
static __device__ __forceinline__ void stc4(float* p, float v) {
    __hip_atomic_store(p, v, __ATOMIC_RELAXED, __HIP_MEMORY_SCOPE_AGENT);
}
static __device__ __forceinline__ void stc2(u16* p, u16 v) {
    __hip_atomic_store(p, v, __ATOMIC_RELAXED, __HIP_MEMORY_SCOPE_AGENT);
}

static __device__ __forceinline__ void dma16(const float* g, float* l) {
    __builtin_amdgcn_global_load_lds((const __attribute__((address_space(1))) void*)g,
                                     (__attribute__((address_space(3))) void*)l, 16, 0, 0);
}

// ---------------- typed barriers ----------------
// bar (u32 idx): moglines (layer*32+i)*32, i<32 -> [0,2048)  (count ONLY mog arrivals)
//                g6lines 2048 + j*32, j<64      -> [2048,4096) (count ONLY g6 arrivals)
//                genM[layer] at 4096+layer*32 ; genG[layer] at 4224+layer*32
static __device__ __forceinline__ void lineAdd(u32* bar, int idx, u32 v) {
    __hip_atomic_fetch_add(bar + idx, v, __ATOMIC_RELAXED, __HIP_MEMORY_SCOPE_AGENT);
}
static __device__ __forceinline__ u32 lsum(u32* bar, int baseIdx, int nl) {
    u32 v = 0;
    if ((int)threadIdx.x < nl)
        v = __hip_atomic_load(bar + baseIdx + (int)threadIdx.x * 32,
                              __ATOMIC_RELAXED, __HIP_MEMORY_SCOPE_AGENT);
    v += __shfl_xor(v, 1);
    v += __shfl_xor(v, 2);
    v += __shfl_xor(v, 4);
    v += __shfl_xor(v, 8);
    v += __shfl_xor(v, 16);
    v += __shfl_xor(v, 32);
    return v;
}
// master: detect sum over lines, release gen; others: poll gen.
static __device__ __forceinline__ void waitGen(u32* bar, int lineBase, int nl, int genIdx,
                                               bool master, u32 t, u32 need) {
    if (master) {
        if (threadIdx.x < 64) {
            for (;;) {
                u32 v = lsum(bar, lineBase, nl);
                if (v >= need) break;
                __builtin_amdgcn_s_sleep(1);
            }
            if (threadIdx.x == 0)
                __hip_atomic_store(bar + genIdx, t, __ATOMIC_RELAXED, __HIP_MEMORY_SCOPE_AGENT);
        }
    } else {
        if (threadIdx.x == 0) {
            while (__hip_atomic_load(bar + genIdx, __ATOMIC_RELAXED,
                                     __HIP_MEMORY_SCOPE_AGENT) < t)
                __builtin_amdgcn_s_sleep(1);
        }
    }
    __builtin_amdgcn_s_barrier();
    asm volatile("" ::: "memory");
}

// ---------------- weight staging (self-staged) ----------------
// mog: 16 rows x 1024 k fp32 = 64KB; LDS float idx = oct*128 + row*8 + half*4.
static __device__ __forceinline__ void stage_mogF(const float* W, int jb, float* lbuf,
                                                  int lane, int wv) {
    int oct2 = lane >> 5, row = (lane >> 1) & 15, half = lane & 1;
#pragma unroll
    for (int i = 0; i < 16; ++i) {
        int og = wv * 16 + i;
        const float* src = W + (size_t)(jb + row) * 1024 + (og * 2 + oct2) * 8 + half * 4;
        dma16(src, lbuf + og * 256);
    }
}
// lstm chunk: 64 rows x 128 k = 32KB; idx = octl*512 + rowc*8 + half*4.
static __device__ __forceinline__ void stage_l128(const float* Ws, int jb, int kb,
                                                  float* lbuf, int lane, int wv) {
    int half = lane & 1;
#pragma unroll
    for (int i = 0; i < 8; ++i) {
        int octl = wv * 4 + (i >> 1);
        int rh = i & 1;
        int rowc = rh * 32 + (lane >> 1);
        int grow = (rowc >> 4) * 1024 + jb + (rowc & 15);
        const float* src = Ws + (size_t)grow * 1024 + kb + octl * 8 + half * 4;
        dma16(src, lbuf + octl * 512 + rh * 256);
    }
}

// ---------------- lstm chunk pieces ----------------
static __device__ __forceinline__ void l_acts(const u16* aH, const u16* aL, int cidx,
                                              int lane, int wv, bf16x8 fr[4]) {
    const int col = lane & 15, kq4 = lane >> 4;
    size_t octa = (size_t)cidx * 16 + wv * 4 + kq4;
    const u16* pH = aH + (octa * 32 + col) * 8;
    const u16* pL = aL + (octa * 32 + col) * 8;
    fr[0] = ldA(pH);
    fr[1] = ldA(pH + 128);
    fr[2] = ldA(pL);
    fr[3] = ldA(pL + 128);
}
static __device__ __forceinline__ void l_mfma(const float* lbuf, const bf16x8 fr[4],
                                              int lane, int wv, f32x4 (&acc)[4][2]) {
    const int col = lane & 15, kq4 = lane >> 4;
    const float* wbase = lbuf + (wv * 4 + kq4) * 512;
#pragma unroll
    for (int rt = 0; rt < 4; ++rt) {
        const float* wp = wbase + (rt * 16 + col) * 8;
        f32x4 w0 = *(const f32x4*)wp, w1 = *(const f32x4*)(wp + 4);
        bf16x8 whi = mkfrag(pkhi(w0.x, w0.y), pkhi(w0.z, w0.w),
                            pkhi(w1.x, w1.y), pkhi(w1.z, w1.w));
        bf16x8 wlo = mkfrag(pklo(w0.x, w0.y), pklo(w0.z, w0.w),
                            pklo(w1.x, w1.y), pklo(w1.z, w1.w));
        acc[rt][0] = __builtin_amdgcn_mfma_f32_16x16x32_bf16(fr[0], whi, acc[rt][0], 0, 0, 0);
        acc[rt][0] = __builtin_amdgcn_mfma_f32_16x16x32_bf16(fr[2], whi, acc[rt][0], 0, 0, 0);
        acc[rt][0] = __builtin_amdgcn_mfma_f32_16x16x32_bf16(fr[0], wlo, acc[rt][0], 0, 0, 0);
        acc[rt][1] = __builtin_amdgcn_mfma_f32_16x16x32_bf16(fr[1], whi, acc[rt][1], 0, 0, 0);
        acc[rt][1] = __builtin_amdgcn_mfma_f32_16x16x32_bf16(fr[3], whi, acc[rt][1], 0, 0, 0);
        acc[rt][1] = __builtin_amdgcn_mfma_f32_16x16x32_bf16(fr[1], wlo, acc[rt][1], 0, 0, 0);
    }
}

// ---------------- persistent recurrence kernel ----------------
struct RArgs {
    const float *m1W, *m1b, *Wih1, *Whh1, *bih1, *bhh1;
    const float *m2W, *m2b, *Wih2, *Whh2, *bih2, *bhh2;
    float* XTF;
    u16 *XTH, *XTL;
    float* stF;
    u16* stH;
    float* hs;
    u32* bar;
};

__global__ __launch_bounds__(256, 1) void reck(RArgs A) {
    __shared__ float wbuf[4][8192];   // 4 x 32KB (mog: 2 x 64KB)
    __shared__ float red[4][32][16];  // 8KB

    const int tid = threadIdx.x, lane = tid & 63, wv = tid >> 6;
    const int col = lane & 15, kq4 = lane >> 4;
    const int blk = blockIdx.x;
    const int layer = blk >> 7;
    const int g = blk & 127;
    const bool isMog = g < 64;
    const bool masterM = (g == 0);
    const bool masterG = (g == 64);
    const int moglineIdx = layer * 1024 + (g & 31) * 32;
    const int g6lineIdx  = 2048 + (blk & 63) * 32;
    const int genMi = 4096 + layer * 32;
    const int genGi = 4224 + layer * 32;
    const int jb = (g & 63) * 16;

    const float* mW  = layer ? A.m2W : A.m1W;
    const float* mb_ = layer ? A.m2b : A.m1b;
    const float* Wih = layer ? A.Wih2 : A.Wih1;
    const float* Whh = layer ? A.Whh2 : A.Whh1;
    const float* bih = layer ? A.bih2 : A.bih1;
    const float* bhh = layer ? A.bhh2 : A.bhh1;

    float* hF  = A.stF + layer * 32768;
    float* hmF = A.stF + 65536 + layer * 32768;
    float* cS  = A.stF + 131072 + layer * 32768;
    float* rFb = A.stF + 196608;
    u16* hH  = A.stH + layer * 32768;
    u16* hmH = A.stH + 65536 + layer * 32768;
    u16* rHb = A.stH + 131072;
    u16* hL  = A.stH + 196608 + layer * 32768;
    u16* hmL = A.stH + 262144 + layer * 32768;
    u16* rLb = A.stH + 327680;

    float* mbuf0 = &wbuf[0][0];
    float* mbuf1 = &wbuf[2][0];

    u32 mgbase = 0;
    int cur = 0;

    if (isMog) {
        stage_mogF(mW, jb, mbuf0, lane, wv);   // prologue: ph0 weights
        asm volatile("s_waitcnt vmcnt(0)" ::: "memory");
    }
    __builtin_amdgcn_s_barrier();

    for (int s = 0; s <= 64; ++s) {
        const bool act = layer ? (s > 0) : (s < 64);
        const int t = layer ? s - 1 : s;
        const int tt = act ? t : 0;
        const int rb = tt & 1;

        float* xF; u16 *xH, *xL;
        if (layer == 0) {
            xF = A.XTF + (size_t)tt * 32768;
            xH = A.XTH + (size_t)tt * 32768;
            xL = A.XTL + (size_t)tt * 32768;
        } else {
            xF = rFb + rb * 32768;
            xH = rHb + rb * 32768;
            xL = rLb + rb * 32768;
        }

        if (isMog) {
            if (act) {
                for (int ph = 0; ph < 5; ++ph) {
                    float* wsrc = cur ? mbuf1 : mbuf0;
                    float* wdst = cur ? mbuf0 : mbuf1;
                    const u16 *gH, *gL; const float* srcF; float* dF; u16 *dH, *dL;
                    switch (ph) {
                        case 0:  gH = hH;  gL = hL;  srcF = xF;  dF = xF;  dH = xH;  dL = xL;  break;
                        case 1:  gH = xH;  gL = xL;  srcF = hF;  dF = hmF; dH = hmH; dL = hmL; break;
                        case 2:  gH = hmH; gL = hmL; srcF = xF;  dF = xF;  dH = xH;  dL = xL;  break;
                        case 3:  gH = xH;  gL = xL;  srcF = hmF; dF = hmF; dH = hmH; dL = hmL; break;
                        default: gH = hmH; gL = hmL; srcF = xF;  dF = xF;  dH = xH;  dL = xL;  break;
                    }
                    // acts first
                    bf16x8 AH0[8], AH1[8], AL0[8], AL1[8];
#pragma unroll
                    for (int kt = 0; kt < 8; ++kt) {
                        int octc = wv * 32 + kt * 4 + kq4;
                        const u16* pH = gH + ((size_t)octc * 32 + col) * 8;
                        const u16* pL = gL + ((size_t)octc * 32 + col) * 8;
                        AH0[kt] = ldA(pH);  AH1[kt] = ldA(pH + 128);
                        AL0[kt] = ldA(pL);  AL1[kt] = ldA(pL + 128);
                    }
                    // srcF prefetch (off the post-reduce critical path)
                    float sF[2];
                    size_t pidxv[2];
#pragma unroll
                    for (int uu = 0; uu < 2; ++uu) {
                        int u = tid + uu * 256;
                        int jj = u & 15, bb = u >> 4;
                        int d = jb + jj;
                        pidxv[uu] = ((size_t)(d >> 3) * 32 + bb) * 8 + (d & 7);
                        sF[uu] = ldc4(srcF + pidxv[uu]);
                    }
                    // next-phase stage: flies under MFMA+reduce, drained at arrival
                    stage_mogF(mW + (size_t)((ph + 1) % 5) * 1048576, jb, wdst, lane, wv);
                    // MFMA (weights in wsrc drained at previous arrival)
                    f32x4 a0 = {0.f, 0.f, 0.f, 0.f}, a1 = {0.f, 0.f, 0.f, 0.f};
#pragma unroll
                    for (int kt = 0; kt < 8; ++kt) {
                        int octc = wv * 32 + kt * 4 + kq4;
                        const float* wp = wsrc + octc * 128 + col * 8;
                        f32x4 w0 = *(const f32x4*)wp, w1 = *(const f32x4*)(wp + 4);
                        bf16x8 whi = mkfrag(pkhi(w0.x, w0.y), pkhi(w0.z, w0.w),
                                            pkhi(w1.x, w1.y), pkhi(w1.z, w1.w));
                        bf16x8 wlo = mkfrag(pklo(w0.x, w0.y), pklo(w0.z, w0.w),
                                            pklo(w1.x, w1.y), pklo(w1.z, w1.w));
                        a0 = __builtin_amdgcn_mfma_f32_16x16x32_bf16(AH0[kt], whi, a0, 0, 0, 0);
                        a0 = __builtin_amdgcn_mfma_f32_16x16x32_bf16(AL0[kt], whi, a0, 0, 0, 0);
                        a0 = __builtin_amdgcn_mfma_f32_16x16x32_bf16(AH0[kt], wlo, a0, 0, 0, 0);
                        a1 = __builtin_amdgcn_mfma_f32_16x16x32_bf16(AH1[kt], whi, a1, 0, 0, 0);
                        a1 = __builtin_amdgcn_mfma_f32_16x16x32_bf16(AL1[kt], whi, a1, 0, 0, 0);
                        a1 = __builtin_amdgcn_mfma_f32_16x16x32_bf16(AH1[kt], wlo, a1, 0, 0, 0);
                    }
#pragma unroll
                    for (int mh = 0; mh < 2; ++mh) {
                        f32x4 av = mh ? a1 : a0;
#pragma unroll
                        for (int r = 0; r < 4; ++r)
                            red[wv][mh * 16 + kq4 * 4 + r][col] = av[r];
                    }
                    __syncthreads();
#pragma unroll
                    for (int uu = 0; uu < 2; ++uu) {
                        int u = tid + uu * 256;
                        int jj = u & 15, bb = u >> 4;
                        float sv = red[0][bb][jj] + red[1][bb][jj]
                                 + red[2][bb][jj] + red[3][bb][jj];
                        int d = jb + jj;
                        sv += mb_[ph * 1024 + d];
                        float gate = 2.0f * sigmoidf_(sv);
                        float val = gate * sF[uu];
                        stc4(dF + pidxv[uu], val);
                        u32 uv = __float_as_uint(val);
                        stc2(dH + pidxv[uu], (u16)(uv >> 16));
                        float lov = val - __uint_as_float(uv & 0xffff0000u);
                        stc2(dL + pidxv[uu], (u16)(__float_as_uint(lov) >> 16));
                    }
                    // arrival: drain stage residual + publish stores, then count
                    asm volatile("s_waitcnt vmcnt(0) lgkmcnt(0)" ::: "memory");
                    __builtin_amdgcn_s_barrier();
                    if (tid == 0) lineAdd(A.bar, moglineIdx, 1);
                    if (ph < 4)
                        waitGen(A.bar, layer * 1024, 32, genMi, masterM,
                                mgbase + ph + 1, (mgbase + ph + 1) << 6);
                    cur ^= 1;
                }
                // master releases b5 for lstm (no wait for other mog blocks)
                if (masterM) {
                    if (tid < 64) {
                        for (;;) {
                            u32 v = lsum(A.bar, layer * 1024, 32);
                            if (v >= ((mgbase + 5) << 6)) break;
                            __builtin_amdgcn_s_sleep(1);
                        }
                        if (tid == 0)
                            __hip_atomic_store(A.bar + genMi, mgbase + 5,
                                               __ATOMIC_RELAXED, __HIP_MEMORY_SCOPE_AGENT);
                    }
                }
                __builtin_amdgcn_s_barrier();
                if (tid == 0) lineAdd(A.bar, g6lineIdx, 1);
            } else {
                __builtin_amdgcn_s_barrier();
                if (tid == 0) {
                    lineAdd(A.bar, moglineIdx, 5);   // keep counts homogeneous
                    lineAdd(A.bar, g6lineIdx, 1);
                }
            }
            waitGen(A.bar, 2048, 64, genGi, false, (u32)(s + 1), (u32)(s + 1) << 8);
        } else {
            // ---------- LSTM block ----------
            if (act) {
                const bool firstAct = layer ? (s == 1) : (s == 0);
                const bool nextAct = layer ? (s < 64) : (s < 63);
                if (firstAct) {
#pragma unroll
                    for (int c = 0; c < 3; ++c)
                        stage_l128(Whh, jb, c * 128, &wbuf[c][0], lane, wv);
                }
                // single wait: hm final (end of ph3)
                waitGen(A.bar, layer * 1024, 32, genMi, false, mgbase + 4, 0);
                f32x4 acc[4][2];
#pragma unroll
                for (int rt = 0; rt < 4; ++rt) {
                    acc[rt][0] = (f32x4){0.f, 0.f, 0.f, 0.f};
                    acc[rt][1] = (f32x4){0.f, 0.f, 0.f, 0.f};
                }
                bf16x8 frA[4], frB[4];
                l_acts(hmH, hmL, 0, lane, wv, frA);
#pragma unroll
                for (int c = 0; c < 8; ++c) {         // Whh side (overlaps mog ph4)
                    if (c < 7) {
                        if (c & 1) l_acts(hmH, hmL, c + 1, lane, wv, frA);
                        else       l_acts(hmH, hmL, c + 1, lane, wv, frB);
                    }
                    asm volatile("s_waitcnt vmcnt(32)" ::: "memory");
                    int cn = c + 3;
                    if (cn < 8) stage_l128(Whh, jb, cn * 128, &wbuf[cn & 3][0], lane, wv);
                    else        stage_l128(Wih, jb, (cn - 8) * 128, &wbuf[cn & 3][0], lane, wv);
                    if (c & 1) l_mfma(&wbuf[c & 3][0], frB, lane, wv, acc);
                    else       l_mfma(&wbuf[c & 3][0], frA, lane, wv, acc);
                }
                // x ready (end of ph4)
                waitGen(A.bar, layer * 1024, 32, genMi, false, mgbase + 5, 0);
                l_acts(xH, xL, 0, lane, wv, frA);
#pragma unroll
                for (int c = 0; c < 8; ++c) {         // Wih side
                    if (c < 7) {
                        if (c & 1) l_acts(xH, xL, c + 1, lane, wv, frA);
                        else       l_acts(xH, xL, c + 1, lane, wv, frB);
                    }
                    asm volatile("s_waitcnt vmcnt(32)" ::: "memory");
                    int cn = c + 3;
                    if (cn < 8) stage_l128(Wih, jb, cn * 128, &wbuf[cn & 3][0], lane, wv);
                    if (c & 1) l_mfma(&wbuf[c & 3][0], frB, lane, wv, acc);
                    else       l_mfma(&wbuf[c & 3][0], frA, lane, wv, acc);
                }
                // cross-wave K reduction, gates, state update
                float gv[2][4];
#pragma unroll
                for (int gt = 0; gt < 4; ++gt) {
                    __syncthreads();
#pragma unroll
                    for (int mh = 0; mh < 2; ++mh) {
                        f32x4 av = acc[gt][mh];
#pragma unroll
                        for (int r = 0; r < 4; ++r)
                            red[wv][mh * 16 + kq4 * 4 + r][col] = av[r];
                    }
                    __syncthreads();
#pragma unroll
                    for (int uu = 0; uu < 2; ++uu) {
                        int u = tid + uu * 256;
                        gv[uu][gt] = red[0][u >> 4][u & 15] + red[1][u >> 4][u & 15]
                                   + red[2][u >> 4][u & 15] + red[3][u >> 4][u & 15];
                    }
                }
#pragma unroll
                for (int uu = 0; uu < 2; ++uu) {
                    int u = tid + uu * 256;
                    int cell = u & 15, bb = u >> 4;
                    int d = jb + cell;
                    float gi = gv[uu][0] + bih[d] + bhh[d];
                    float gf = gv[uu][1] + bih[1024 + d] + bhh[1024 + d];
                    float gg = gv[uu][2] + bih[2048 + d] + bhh[2048 + d];
                    float go = gv[uu][3] + bih[3072 + d] + bhh[3072 + d];
                    int cidx = d * 32 + bb;
                    float cn = sigmoidf_(gf) * cS[cidx] + sigmoidf_(gi) * tanhf_(gg);
                    cS[cidx] = cn;
                    float hn = sigmoidf_(go) * tanhf_(cn);
                    size_t pidx = ((size_t)(d >> 3) * 32 + bb) * 8 + (d & 7);
                    u32 uv = __float_as_uint(hn);
                    u16 hhi = (u16)(uv >> 16);
                    float lov = hn - __uint_as_float(uv & 0xffff0000u);
                    u16 hlo = (u16)(__float_as_uint(lov) >> 16);
                    stc4(hF + pidx, hn);
                    stc2(hH + pidx, hhi);
                    stc2(hL + pidx, hlo);
                    if (layer == 0) {
                        int wb = s & 1;
                        stc4(rFb + wb * 32768 + pidx, hn);
                        stc2(rHb + wb * 32768 + pidx, hhi);
                        stc2(rLb + wb * 32768 + pidx, hlo);
                    } else {
                        A.hs[(size_t)bb * 65536 + (size_t)t * 1024 + d] = hn;
                    }
                }
                // g6 arrival: publish h, then count
                asm volatile("s_waitcnt vmcnt(0) lgkmcnt(0)" ::: "memory");
                __builtin_amdgcn_s_barrier();
                if (tid == 0) lineAdd(A.bar, g6lineIdx, 1);
                if (nextAct) {                        // next-slot Whh c0..c2 fly through g6
#pragma unroll
                    for (int c = 0; c < 3; ++c)
                        stage_l128(Whh, jb, c * 128, &wbuf[c][0], lane, wv);
                }
            } else {
                __builtin_amdgcn_s_barrier();
                if (tid == 0) lineAdd(A.bar, g6lineIdx, 1);
            }
            waitGen(A.bar, 2048, 64, genGi, masterG, (u32)(s + 1), (u32)(s + 1) << 8);
        }
        mgbase += 5;
    }
}

// ---------------- embedding gather into fp32 + hi/lo bf16 planes ----------------
__global__ __launch_bounds__(256) void gather_embed(const int* __restrict__ seq,
                                                    const float* __restrict__ emb,
                                                    float* __restrict__ XTF,
                                                    u16* __restrict__ XTH,
                                                    u16* __restrict__ XTL) {
    int t = blockIdx.x;
#pragma unroll 4
    for (int i = 0; i < 16; ++i) {
        int u = i * 256 + threadIdx.x;
        int oct = u >> 5, b = u & 31;
        int row = seq[b * 64 + t];
        const float* sp = emb + (size_t)row * 1024 + oct * 8;
        float4 f0 = *(const float4*)sp;
        float4 f1 = *(const float4*)(sp + 4);
        size_t base = (size_t)t * 32768 + ((size_t)oct * 32 + b) * 8;
        *(float4*)(XTF + base) = f0;
        *(float4*)(XTF + base + 4) = f1;
        u32x4 hi = {pkhi(f0.x, f0.y), pkhi(f0.z, f0.w), pkhi(f1.x, f1.y), pkhi(f1.z, f1.w)};
        u32x4 lo = {pklo(f0.x, f0.y), pklo(f0.z, f0.w), pklo(f1.x, f1.y), pklo(f1.z, f1.w)};
        *(u32x4*)(XTH + base) = hi;
        *(u32x4*)(XTL + base) = lo;
    }
}

// ---------------- fp32 -> bf16 (RNE, projection A) ----------------
__global__ __launch_bounds__(256) void f32_to_bf16(const float* __restrict__ in,
                                                   unsigned short* __restrict__ out, int n) {
    int i = (blockIdx.x * 256 + threadIdx.x) * 8;
    if (i + 7 < n) {
        float4 f0 = *(const float4*)(in + i);
        float4 f1 = *(const float4*)(in + i + 4);
        bf16x8 v;
        v[0] = (short)f2bf(f0.x); v[1] = (short)f2bf(f0.y);
        v[2] = (short)f2bf(f0.z); v[3] = (short)f2bf(f0.w);
        v[4] = (short)f2bf(f1.x); v[5] = (short)f2bf(f1.y);
        v[6] = (short)f2bf(f1.z); v[7] = (short)f2bf(f1.w);
        *(bf16x8*)(out + i) = v;
    }
}

// ---------------- output projection (bf16 MFMA, 128x128 tile) ----------------
__global__ __launch_bounds__(256) void out_proj(const unsigned short* __restrict__ hsb,
                                                const float* __restrict__ emb,
                                                const float* __restrict__ fcb,
                                                float* __restrict__ out) {
    __shared__ unsigned short Al[128 * 40];
    __shared__ unsigned short Bl[128 * 40];
    int tid = threadIdx.x;
    int n0 = blockIdx.x * 128;
    int m0 = blockIdx.y * 128;
    int wid = tid >> 6, l = tid & 63;
    int wm = wid >> 1, wn = wid & 1;
    int c16 = l & 15, kg = l >> 4;

    f32x4 acc[4][4];
#pragma unroll
    for (int i = 0; i < 4; i++)
#pragma unroll
        for (int j = 0; j < 4; j++) acc[i][j] = (f32x4){0.f, 0.f, 0.f, 0.f};

    for (int k0 = 0; k0 < 1024; k0 += 32) {
#pragma unroll
        for (int i = 0; i < 2; i++) {
            int id = i * 256 + tid;
            int r = id >> 2, ccc = id & 3;
            *(bf16x8*)&Al[r * 40 + ccc * 8] =
                *(const bf16x8*)(hsb + (size_t)(m0 + r) * 1024 + k0 + ccc * 8);
        }
#pragma unroll
        for (int i = 0; i < 2; i++) {
            int id = i * 256 + tid;
            int r = id >> 2, ccc = id & 3;
            const float* src = emb + (size_t)(n0 + r) * 1024 + k0 + ccc * 8;
            float4 f0 = *(const float4*)(src);
            float4 f1 = *(const float4*)(src + 4);
            bf16x8 v;
            v[0] = (short)f2bf(f0.x); v[1] = (short)f2bf(f0.y);
            v[2] = (short)f2bf(f0.z); v[3] = (short)f2bf(f0.w);
            v[4] = (short)f2bf(f1.x); v[5] = (short)f2bf(f1.y);
            v[6] = (short)f2bf(f1.z); v[7] = (short)f2bf(f1.w);
            *(bf16x8*)&Bl[r * 40 + ccc * 8] = v;
        }
        __syncthreads();

        bf16x8 afr[4], bfr[4];
#pragma unroll
        for (int i = 0; i < 4; i++)
            afr[i] = *(const bf16x8*)&Al[(wm * 64 + i * 16 + c16) * 40 + kg * 8];
#pragma unroll
        for (int j = 0; j < 4; j++)
            bfr[j] = *(const bf16x8*)&Bl[(wn * 64 + j * 16 + c16) * 40 + kg * 8];
#pragma unroll
        for (int i = 0; i < 4; i++)
#pragma unroll
            for (int j = 0; j < 4; j++)
                acc[i][j] = __builtin_amdgcn_mfma_f32_16x16x32_bf16(afr[i], bfr[j], acc[i][j], 0, 0, 0);
        __syncthreads();
    }

#pragma unroll
    for (int i = 0; i < 4; i++) {
        int row = m0 + wm * 64 + i * 16 + kg * 4;
#pragma unroll
        for (int j = 0; j < 4; j++) {
            int col = n0 + wn * 64 + j * 16 + c16;
            float fb = fcb[col];
#pragma unroll
            for (int r = 0; r < 4; r++)
                out[(size_t)(row + r) * 32000 + col] = acc[i][j][r] + fb;
        }
    }
}

// ---------------- host ----------------
extern "C" void kernel_launch(void* const* d_in, const int* in_sizes, int n_in,
                              void* d_out, int out_size, void* d_ws, size_t ws_size,
                              hipStream_t stream) {
    const int*   seq    = (const int*)d_in[0];
    const float* emb    = (const float*)d_in[2];
    const float* mog1_W = (const float*)d_in[3];
    const float* mog1_b = (const float*)d_in[4];
    const float* W_ih1  = (const float*)d_in[5];
    const float* W_hh1  = (const float*)d_in[6];
    const float* b_ih1  = (const float*)d_in[7];
    const float* b_hh1  = (const float*)d_in[8];
    const float* mog2_W = (const float*)d_in[9];
    const float* mog2_b = (const float*)d_in[10];
    const float* W_ih2  = (const float*)d_in[11];
    const float* W_hh2  = (const float*)d_in[12];
    const float* b_ih2  = (const float*)d_in[13];
    const float* b_hh2  = (const float*)d_in[14];
    const float* fc_b   = (const float*)d_in[15];

    char* ws = (char*)d_ws;
    float* XTF = (float*)ws;                                  // 8 MB
    u16*   XTH = (u16*)(ws + 8388608);                        // 4 MB
    u16*   XTL = (u16*)(ws + 12582912);                       // 4 MB
    float* stF = (float*)(ws + 16777216);                     // 1 MB
    u16*   stH = (u16*)(ws + 17825792);                       // 768 KB
    u32*   bar = (u32*)(ws + 18874368);                       // 32 KB (typed barrier lines)
    unsigned short* hsb = (unsigned short*)(ws + 18907136);   // 4 MB

    float* out0 = (float*)d_out;
    float* hs   = out0 + 65536000LL;

    (void)hipMemsetAsync(stF, 0, 1835008, stream);
    (void)hipMemsetAsync(bar, 0, 32768, stream);

    gather_embed<<<64, 256, 0, stream>>>(seq, emb, XTF, XTH, XTL);

    RArgs a;
    a.m1W = mog1_W; a.m1b = mog1_b;
    a.Wih1 = W_ih1; a.Whh1 = W_hh1; a.bih1 = b_ih1; a.bhh1 = b_hh1;
    a.m2W = mog2_W; a.m2b = mog2_b;
    a.Wih2 = W_ih2; a.Whh2 = W_hh2; a.bih2 = b_ih2; a.bhh2 = b_hh2;
    a.XTF = XTF; a.XTH = XTH; a.XTL = XTL;
    a.stF = stF; a.stH = stH; a.hs = hs; a.bar = bar;

    reck<<<256, 256, 0, stream>>>(a);

    f32_to_bf16<<<1024, 256, 0, stream>>>(hs, hsb, 2097152);
    out_proj<<<dim3(250, 16), 256, 0, stream>>>(hsb, emb, fc_b, out0);
}

// Round 13
// 4429.936 us; speedup vs baseline: 1.0009x; 1.0009x over previous
//
#include <hip/hip_runtime.h>

typedef short bf16x8 __attribute__((ext_vector_type(8)));
typedef float f32x4 __attribute__((ext_vector_type(4)));
typedef unsigned int u32;
typedef u32 u32x4 __attribute__((ext_vector_type(4)));
typedef unsigned short u16;
typedef unsigned long long u64;

static __device__ __forceinline__ unsigned short f2bf(float f) {
    unsigned int u = __float_as_uint(f);
    unsigned int r = (u + 0x7fffu + ((u >> 16) & 1u)) >> 16;
    return (unsigned short)r;
}
static __device__ __forceinline__ float sigmoidf_(float x) {
    return 1.0f / (1.0f + __expf(-x));
}
static __device__ __forceinline__ float tanhf_(float x) {
    return 2.0f / (1.0f + __expf(-2.0f * x)) - 1.0f;
}

// truncation-split packing: fp32 -> (hi bf16, lo bf16)
static __device__ __forceinline__ u32 pkhi(float a, float b) {
    return (__float_as_uint(a) >> 16) | (__float_as_uint(b) & 0xffff0000u);
}
static __device__ __forceinline__ u32 pklo(float a, float b) {
    float la = a - __uint_as_float(__float_as_uint(a) & 0xffff0000u);
    float lb = b - __uint_as_float(__float_as_uint(b) & 0xffff0000u);
    return (__float_as_uint(la) >> 16) | (__float_as_uint(lb) & 0xffff0000u);
}
static __device__ __forceinline__ bf16x8 mkfrag(u32 a, u32 b, u32 c, u32 d) {
    u32x4 v = {a, b, c, d};
    return __builtin_bit_cast(bf16x8, v);
}

// ---- sc1 coherent activation access (fence-free scheme, proven R5+) ----
static __device__ __forceinline__ bf16x8 ldA(const u16* p) {
    u64 a = __hip_atomic_load((const u64*)p, __ATOMIC_RELAXED, __HIP_MEMORY_SCOPE_AGENT);
    u64 b = __hip_atomic_load((const u64*)(p + 4), __ATOMIC_RELAXED, __HIP_MEMORY_SCOPE_AGENT);
    union { u64 q[2]; bf16x8 v; } u;
    u.q[0] = a; u.q[1] = b;
    return u.v;
}
static __device__ __forceinline__ float ldc4(const float* p) {
    return __hip_atomic_load(p, __ATOMIC_RELAXED, __HIP_MEMORY_SCOPE_AGENT);
}
static __device__ __forceinline__ void stc4(float* p, float v) {
    __hip_atomic_store(p, v, __ATOMIC_RELAXED, __HIP_MEMORY_SCOPE_AGENT);
}
static __device__ __forceinline__ void stc2(u16* p, u16 v) {
    __hip_atomic_store(p, v, __ATOMIC_RELAXED, __HIP_MEMORY_SCOPE_AGENT);
}

static __device__ __forceinline__ void dma16(const float* g, float* l) {
    __builtin_amdgcn_global_load_lds((const __attribute__((address_space(1))) void*)g,
                                     (__attribute__((address_space(3))) void*)l, 16, 0, 0);
}

// ---------------- typed barriers with fanned-out release ----------------
// bar (u32 idx): moglines (layer*32+i)*32, i<32 -> [0,2048)   (ONLY mog arrivals)
//                g6lines 2048 + j*32, j<64       -> [2048,4096) (ONLY g6 arrivals)
//                genM[layer]: 16 copies at 4096 + layer*512 + c*32   (c<16)
//                genG[layer]: 16 copies at 5120 + layer*512 + c*32
static __device__ __forceinline__ void lineAdd(u32* bar, int idx, u32 v) {
    __hip_atomic_fetch_add(bar + idx, v, __ATOMIC_RELAXED, __HIP_MEMORY_SCOPE_AGENT);
}
static __device__ __forceinline__ u32 lsum(u32* bar, int baseIdx, int nl) {
    u32 v = 0;
    if ((int)threadIdx.x < nl)
        v = __hip_atomic_load(bar + baseIdx + (int)threadIdx.x * 32,
                              __ATOMIC_RELAXED, __HIP_MEMORY_SCOPE_AGENT);
    v += __shfl_xor(v, 1);
    v += __shfl_xor(v, 2);
    v += __shfl_xor(v, 4);
    v += __shfl_xor(v, 8);
    v += __shfl_xor(v, 16);
    v += __shfl_xor(v, 32);
    return v;
}
static __device__ __forceinline__ void genRelease(u32* bar, int genIdx, u32 t) {
    if (threadIdx.x < 16)
        __hip_atomic_store(bar + genIdx + (int)threadIdx.x * 32, t,
                           __ATOMIC_RELAXED, __HIP_MEMORY_SCOPE_AGENT);
}
// master: detect sum over lines, release 16 gen copies; others: poll own copy.
static __device__ __forceinline__ void waitGen(u32* bar, int lineBase, int nl, int genIdx,
                                               bool master, u32 t, u32 need, int myc) {
    if (master) {
        if (threadIdx.x < 64) {
            for (;;) {
                u32 v = lsum(bar, lineBase, nl);
                if (v >= need) break;
                __builtin_amdgcn_s_sleep(1);
            }
            genRelease(bar, genIdx, t);
        }
    } else {
        if (threadIdx.x == 0) {
            while (__hip_atomic_load(bar + genIdx + myc * 32, __ATOMIC_RELAXED,
                                     __HIP_MEMORY_SCOPE_AGENT) < t)
                __builtin_amdgcn_s_sleep(1);
        }
    }
    __builtin_amdgcn_s_barrier();
    asm volatile("" ::: "memory");
}

// ---------------- weight staging (self-staged) ----------------
// mog: 16 rows x 1024 k fp32 = 64KB; LDS float idx = oct*128 + row*8 + half*4.
static __device__ __forceinline__ void stage_mogF(const float* W, int jb, float* lbuf,
                                                  int lane, int wv) {
    int oct2 = lane >> 5, row = (lane >> 1) & 15, half = lane & 1;
#pragma unroll
    for (int i = 0; i < 16; ++i) {
        int og = wv * 16 + i;
        const float* src = W + (size_t)(jb + row) * 1024 + (og * 2 + oct2) * 8 + half * 4;
        dma16(src, lbuf + og * 256);
    }
}
// lstm chunk: 64 rows x 128 k = 32KB; idx = octl*512 + rowc*8 + half*4.
static __device__ __forceinline__ void stage_l128(const float* Ws, int jb, int kb,
                                                  float* lbuf, int lane, int wv) {
    int half = lane & 1;
#pragma unroll
    for (int i = 0; i < 8; ++i) {
        int octl = wv * 4 + (i >> 1);
        int rh = i & 1;
        int rowc = rh * 32 + (lane >> 1);
        int grow = (rowc >> 4) * 1024 + jb + (rowc & 15);
        const float* src = Ws + (size_t)grow * 1024 + kb + octl * 8 + half * 4;
        dma16(src, lbuf + octl * 512 + rh * 256);
    }
}

// ---------------- lstm chunk pieces ----------------
static __device__ __forceinline__ void l_acts(const u16* aH, const u16* aL, int cidx,
                                              int lane, int wv, bf16x8 fr[4]) {
    const int col = lane & 15, kq4 = lane >> 4;
    size_t octa = (size_t)cidx * 16 + wv * 4 + kq4;
    const u16* pH = aH + (octa * 32 + col) * 8;
    const u16* pL = aL + (octa * 32 + col) * 8;
    fr[0] = ldA(pH);
    fr[1] = ldA(pH + 128);
    fr[2] = ldA(pL);
    fr[3] = ldA(pL + 128);
}
static __device__ __forceinline__ void l_mfma(const float* lbuf, const bf16x8 fr[4],
                                              int lane, int wv, f32x4 (&acc)[4][2]) {
    const int col = lane & 15, kq4 = lane >> 4;
    const float* wbase = lbuf + (wv * 4 + kq4) * 512;
#pragma unroll
    for (int rt = 0; rt < 4; ++rt) {
        const float* wp = wbase + (rt * 16 + col) * 8;
        f32x4 w0 = *(const f32x4*)wp, w1 = *(const f32x4*)(wp + 4);
        bf16x8 whi = mkfrag(pkhi(w0.x, w0.y), pkhi(w0.z, w0.w),
                            pkhi(w1.x, w1.y), pkhi(w1.z, w1.w));
        bf16x8 wlo = mkfrag(pklo(w0.x, w0.y), pklo(w0.z, w0.w),
                            pklo(w1.x, w1.y), pklo(w1.z, w1.w));
        acc[rt][0] = __builtin_amdgcn_mfma_f32_16x16x32_bf16(fr[0], whi, acc[rt][0], 0, 0, 0);
        acc[rt][0] = __builtin_amdgcn_mfma_f32_16x16x32_bf16(fr[2], whi, acc[rt][0], 0, 0, 0);
        acc[rt][0] = __builtin_amdgcn_mfma_f32_16x16x32_bf16(fr[0], wlo, acc[rt][0], 0, 0, 0);
        acc[rt][1] = __builtin_amdgcn_mfma_f32_16x16x32_bf16(fr[1], whi, acc[rt][1], 0, 0, 0);
        acc[rt][1] = __builtin_amdgcn_mfma_f32_16x16x32_bf16(fr[3], whi, acc[rt][1], 0, 0, 0);
        acc[rt][1] = __builtin_amdgcn_mfma_f32_16x16x32_bf16(fr[1], wlo, acc[rt][1], 0, 0, 0);
    }
}

// ---------------- persistent recurrence kernel ----------------
struct RArgs {
    const float *m1W, *m1b, *Wih1, *Whh1, *bih1, *bhh1;
    const float *m2W, *m2b, *Wih2, *Whh2, *bih2, *bhh2;
    float* XTF;
    u16 *XTH, *XTL;
    float* stF;
    u16* stH;
    float* hs;
    u32* bar;
};

__global__ __launch_bounds__(256, 1) void reck(RArgs A) {
    __shared__ float wbuf[4][8192];   // 4 x 32KB (mog: 2 x 64KB)
    __shared__ float red[4][32][16];  // 8KB

    const int tid = threadIdx.x, lane = tid & 63, wv = tid >> 6;
    const int col = lane & 15, kq4 = lane >> 4;
    const int blk = blockIdx.x;
    const int layer = blk >> 7;
    const int g = blk & 127;
    const bool isMog = g < 64;
    const bool masterM = (g == 0);
    const bool masterG = (g == 64);
    const int moglineIdx = layer * 1024 + (g & 31) * 32;
    const int g6lineIdx  = 2048 + (blk & 63) * 32;
    const int genMi = 4096 + layer * 512;
    const int genGi = 5120 + layer * 512;
    const int myc = blk & 15;
    const int jb = (g & 63) * 16;

    const float* mW  = layer ? A.m2W : A.m1W;
    const float* mb_ = layer ? A.m2b : A.m1b;
    const float* Wih = layer ? A.Wih2 : A.Wih1;
    const float* Whh = layer ? A.Whh2 : A.Whh1;
    const float* bih = layer ? A.bih2 : A.bih1;
    const float* bhh = layer ? A.bhh2 : A.bhh1;

    float* hF  = A.stF + layer * 32768;
    float* hmF = A.stF + 65536 + layer * 32768;
    float* cS  = A.stF + 131072 + layer * 32768;
    float* rFb = A.stF + 196608;
    u16* hH  = A.stH + layer * 32768;
    u16* hmH = A.stH + 65536 + layer * 32768;
    u16* rHb = A.stH + 131072;
    u16* hL  = A.stH + 196608 + layer * 32768;
    u16* hmL = A.stH + 262144 + layer * 32768;
    u16* rLb = A.stH + 327680;

    float* mbuf0 = &wbuf[0][0];
    float* mbuf1 = &wbuf[2][0];

    u32 mgbase = 0;
    int cur = 0;

    if (isMog) {
        stage_mogF(mW, jb, mbuf0, lane, wv);   // prologue: ph0 weights
        asm volatile("s_waitcnt vmcnt(0)" ::: "memory");
    }
    __builtin_amdgcn_s_barrier();

    for (int s = 0; s <= 64; ++s) {
        const bool act = layer ? (s > 0) : (s < 64);
        const int t = layer ? s - 1 : s;
        const int tt = act ? t : 0;
        const int rb = tt & 1;

        float* xF; u16 *xH, *xL;
        if (layer == 0) {
            xF = A.XTF + (size_t)tt * 32768;
            xH = A.XTH + (size_t)tt * 32768;
            xL = A.XTL + (size_t)tt * 32768;
        } else {
            xF = rFb + rb * 32768;
            xH = rHb + rb * 32768;
            xL = rLb + rb * 32768;
        }

        if (isMog) {
            if (act) {
                for (int ph = 0; ph < 5; ++ph) {
                    float* wsrc = cur ? mbuf1 : mbuf0;
                    float* wdst = cur ? mbuf0 : mbuf1;
                    const u16 *gH, *gL; const float* srcF; float* dF; u16 *dH, *dL;
                    switch (ph) {
                        case 0:  gH = hH;  gL = hL;  srcF = xF;  dF = xF;  dH = xH;  dL = xL;  break;
                        case 1:  gH = xH;  gL = xL;  srcF = hF;  dF = hmF; dH = hmH; dL = hmL; break;
                        case 2:  gH = hmH; gL = hmL; srcF = xF;  dF = xF;  dH = xH;  dL = xL;  break;
                        case 3:  gH = xH;  gL = xL;  srcF = hmF; dF = hmF; dH = hmH; dL = hmL; break;
                        default: gH = hmH; gL = hmL; srcF = xF;  dF = xF;  dH = xH;  dL = xL;  break;
                    }
                    // acts first
                    bf16x8 AH0[8], AH1[8], AL0[8], AL1[8];
#pragma unroll
                    for (int kt = 0; kt < 8; ++kt) {
                        int octc = wv * 32 + kt * 4 + kq4;
                        const u16* pH = gH + ((size_t)octc * 32 + col) * 8;
                        const u16* pL = gL + ((size_t)octc * 32 + col) * 8;
                        AH0[kt] = ldA(pH);  AH1[kt] = ldA(pH + 128);
                        AL0[kt] = ldA(pL);  AL1[kt] = ldA(pL + 128);
                    }
                    // srcF prefetch (off the post-reduce critical path)
                    float sF[2];
                    size_t pidxv[2];
#pragma unroll
                    for (int uu = 0; uu < 2; ++uu) {
                        int u = tid + uu * 256;
                        int jj = u & 15, bb = u >> 4;
                        int d = jb + jj;
                        pidxv[uu] = ((size_t)(d >> 3) * 32 + bb) * 8 + (d & 7);
                        sF[uu] = ldc4(srcF + pidxv[uu]);
                    }
                    // next-phase stage: flies under MFMA+reduce, drained at arrival
                    stage_mogF(mW + (size_t)((ph + 1) % 5) * 1048576, jb, wdst, lane, wv);
                    // MFMA (weights in wsrc drained at previous arrival)
                    f32x4 a0 = {0.f, 0.f, 0.f, 0.f}, a1 = {0.f, 0.f, 0.f, 0.f};
#pragma unroll
                    for (int kt = 0; kt < 8; ++kt) {
                        int octc = wv * 32 + kt * 4 + kq4;
                        const float* wp = wsrc + octc * 128 + col * 8;
                        f32x4 w0 = *(const f32x4*)wp, w1 = *(const f32x4*)(wp + 4);
                        bf16x8 whi = mkfrag(pkhi(w0.x, w0.y), pkhi(w0.z, w0.w),
                                            pkhi(w1.x, w1.y), pkhi(w1.z, w1.w));
                        bf16x8 wlo = mkfrag(pklo(w0.x, w0.y), pklo(w0.z, w0.w),
                                            pklo(w1.x, w1.y), pklo(w1.z, w1.w));
                        a0 = __builtin_amdgcn_mfma_f32_16x16x32_bf16(AH0[kt], whi, a0, 0, 0, 0);
                        a0 = __builtin_amdgcn_mfma_f32_16x16x32_bf16(AL0[kt], whi, a0, 0, 0, 0);
                        a0 = __builtin_amdgcn_mfma_f32_16x16x32_bf16(AH0[kt], wlo, a0, 0, 0, 0);
                        a1 = __builtin_amdgcn_mfma_f32_16x16x32_bf16(AH1[kt], whi, a1, 0, 0, 0);
                        a1 = __builtin_amdgcn_mfma_f32_16x16x32_bf16(AL1[kt], whi, a1, 0, 0, 0);
                        a1 = __builtin_amdgcn_mfma_f32_16x16x32_bf16(AH1[kt], wlo, a1, 0, 0, 0);
                    }
#pragma unroll
                    for (int mh = 0; mh < 2; ++mh) {
                        f32x4 av = mh ? a1 : a0;
#pragma unroll
                        for (int r = 0; r < 4; ++r)
                            red[wv][mh * 16 + kq4 * 4 + r][col] = av[r];
                    }
                    __syncthreads();
#pragma unroll
                    for (int uu = 0; uu < 2; ++uu) {
                        int u = tid + uu * 256;
                        int jj = u & 15, bb = u >> 4;
                        float sv = red[0][bb][jj] + red[1][bb][jj]
                                 + red[2][bb][jj] + red[3][bb][jj];
                        int d = jb + jj;
                        sv += mb_[ph * 1024 + d];
                        float gate = 2.0f * sigmoidf_(sv);
                        float val = gate * sF[uu];
                        stc4(dF + pidxv[uu], val);
                        u32 uv = __float_as_uint(val);
                        stc2(dH + pidxv[uu], (u16)(uv >> 16));
                        float lov = val - __uint_as_float(uv & 0xffff0000u);
                        stc2(dL + pidxv[uu], (u16)(__float_as_uint(lov) >> 16));
                    }
                    // arrival: drain stage residual + publish stores, then count
                    asm volatile("s_waitcnt vmcnt(0) lgkmcnt(0)" ::: "memory");
                    __builtin_amdgcn_s_barrier();
                    if (tid == 0) lineAdd(A.bar, moglineIdx, 1);
                    if (ph < 4)
                        waitGen(A.bar, layer * 1024, 32, genMi, masterM,
                                mgbase + ph + 1, (mgbase + ph + 1) << 6, myc);
                    cur ^= 1;
                }
                // master releases b5 for lstm (no wait for other mog blocks)
                if (masterM) {
                    if (tid < 64) {
                        for (;;) {
                            u32 v = lsum(A.bar, layer * 1024, 32);
                            if (v >= ((mgbase + 5) << 6)) break;
                            __builtin_amdgcn_s_sleep(1);
                        }
                        genRelease(A.bar, genMi, mgbase + 5);
                    }
                }
                __builtin_amdgcn_s_barrier();
                if (tid == 0) lineAdd(A.bar, g6lineIdx, 1);
            } else {
                __builtin_amdgcn_s_barrier();
                if (tid == 0) {
                    lineAdd(A.bar, moglineIdx, 5);   // keep counts homogeneous
                    lineAdd(A.bar, g6lineIdx, 1);
                }
            }
            waitGen(A.bar, 2048, 64, genGi, false, (u32)(s + 1), (u32)(s + 1) << 8, myc);
        } else {
            // ---------- LSTM block ----------
            if (act) {
                const bool firstAct = layer ? (s == 1) : (s == 0);
                const bool nextAct = layer ? (s < 64) : (s < 63);
                if (firstAct) {
#pragma unroll
                    for (int c = 0; c < 3; ++c)
                        stage_l128(Whh, jb, c * 128, &wbuf[c][0], lane, wv);
                }
                // single wait: hm final (end of ph3)
                waitGen(A.bar, layer * 1024, 32, genMi, false, mgbase + 4, 0, myc);
                f32x4 acc[4][2];
#pragma unroll
                for (int rt = 0; rt < 4; ++rt) {
                    acc[rt][0] = (f32x4){0.f, 0.f, 0.f, 0.f};
                    acc[rt][1] = (f32x4){0.f, 0.f, 0.f, 0.f};
                }
                bf16x8 frA[4], frB[4];
                l_acts(hmH, hmL, 0, lane, wv, frA);
#pragma unroll
                for (int c = 0; c < 8; ++c) {         // Whh side (overlaps mog ph4)
                    if (c < 7) {
                        if (c & 1) l_acts(hmH, hmL, c + 1, lane, wv, frA);
                        else       l_acts(hmH, hmL, c + 1, lane, wv, frB);
                    }
                    asm volatile("s_waitcnt vmcnt(32)" ::: "memory");
                    int cn = c + 3;
                    if (cn < 8) stage_l128(Whh, jb, cn * 128, &wbuf[cn & 3][0], lane, wv);
                    else        stage_l128(Wih, jb, (cn - 8) * 128, &wbuf[cn & 3][0], lane, wv);
                    if (c & 1) l_mfma(&wbuf[c & 3][0], frB, lane, wv, acc);
                    else       l_mfma(&wbuf[c & 3][0], frA, lane, wv, acc);
                }
                // x ready (end of ph4)
                waitGen(A.bar, layer * 1024, 32, genMi, false, mgbase + 5, 0, myc);
                l_acts(xH, xL, 0, lane, wv, frA);
#pragma unroll
                for (int c = 0; c < 8; ++c) {         // Wih side
                    if (c < 7) {
                        if (c & 1) l_acts(xH, xL, c + 1, lane, wv, frA);
                        else       l_acts(xH, xL, c + 1, lane, wv, frB);
                    }
                    asm volatile("s_waitcnt vmcnt(32)" ::: "memory");
                    int cn = c + 3;
                    if (cn < 8) stage_l128(Wih, jb, cn * 128, &wbuf[cn & 3][0], lane, wv);
                    if (c & 1) l_mfma(&wbuf[c & 3][0], frB, lane, wv, acc);
                    else       l_mfma(&wbuf[c & 3][0], frA, lane, wv, acc);
                }
                // cross-wave K reduction, gates, state update
                float gv[2][4];
#pragma unroll
                for (int gt = 0; gt < 4; ++gt) {
                    __syncthreads();
#pragma unroll
                    for (int mh = 0; mh < 2; ++mh) {
                        f32x4 av = acc[gt][mh];
#pragma unroll
                        for (int r = 0; r < 4; ++r)
                            red[wv][mh * 16 + kq4 * 4 + r][col] = av[r];
                    }
                    __syncthreads();
#pragma unroll
                    for (int uu = 0; uu < 2; ++uu) {
                        int u = tid + uu * 256;
                        gv[uu][gt] = red[0][u >> 4][u & 15] + red[1][u >> 4][u & 15]
                                   + red[2][u >> 4][u & 15] + red[3][u >> 4][u & 15];
                    }
                }
#pragma unroll
                for (int uu = 0; uu < 2; ++uu) {
                    int u = tid + uu * 256;
                    int cell = u & 15, bb = u >> 4;
                    int d = jb + cell;
                    float gi = gv[uu][0] + bih[d] + bhh[d];
                    float gf = gv[uu][1] + bih[1024 + d] + bhh[1024 + d];
                    float gg = gv[uu][2] + bih[2048 + d] + bhh[2048 + d];
                    float go = gv[uu][3] + bih[3072 + d] + bhh[3072 + d];
                    int cidx = d * 32 + bb;
                    float cn = sigmoidf_(gf) * cS[cidx] + sigmoidf_(gi) * tanhf_(gg);
                    cS[cidx] = cn;
                    float hn = sigmoidf_(go) * tanhf_(cn);
                    size_t pidx = ((size_t)(d >> 3) * 32 + bb) * 8 + (d & 7);
                    u32 uv = __float_as_uint(hn);
                    u16 hhi = (u16)(uv >> 16);
                    float lov = hn - __uint_as_float(uv & 0xffff0000u);
                    u16 hlo = (u16)(__float_as_uint(lov) >> 16);
                    stc4(hF + pidx, hn);
                    stc2(hH + pidx, hhi);
                    stc2(hL + pidx, hlo);
                    if (layer == 0) {
                        int wb = s & 1;
                        stc4(rFb + wb * 32768 + pidx, hn);
                        stc2(rHb + wb * 32768 + pidx, hhi);
                        stc2(rLb + wb * 32768 + pidx, hlo);
                    } else {
                        A.hs[(size_t)bb * 65536 + (size_t)t * 1024 + d] = hn;
                    }
                }
                // g6 arrival: publish h, then count
                asm volatile("s_waitcnt vmcnt(0) lgkmcnt(0)" ::: "memory");
                __builtin_amdgcn_s_barrier();
                if (tid == 0) lineAdd(A.bar, g6lineIdx, 1);
                if (nextAct) {                        // next-slot Whh c0..c2 fly through g6
#pragma unroll
                    for (int c = 0; c < 3; ++c)
                        stage_l128(Whh, jb, c * 128, &wbuf[c][0], lane, wv);
                }
            } else {
                __builtin_amdgcn_s_barrier();
                if (tid == 0) lineAdd(A.bar, g6lineIdx, 1);
            }
            waitGen(A.bar, 2048, 64, genGi, masterG, (u32)(s + 1), (u32)(s + 1) << 8, myc);
        }
        mgbase += 5;
    }
}

// ---------------- embedding gather into fp32 + hi/lo bf16 planes ----------------
__global__ __launch_bounds__(256) void gather_embed(const int* __restrict__ seq,
                                                    const float* __restrict__ emb,
                                                    float* __restrict__ XTF,
                                                    u16* __restrict__ XTH,
                                                    u16* __restrict__ XTL) {
    int t = blockIdx.x;
#pragma unroll 4
    for (int i = 0; i < 16; ++i) {
        int u = i * 256 + threadIdx.x;
        int oct = u >> 5, b = u & 31;
        int row = seq[b * 64 + t];
        const float* sp = emb + (size_t)row * 1024 + oct * 8;
        float4 f0 = *(const float4*)sp;
        float4 f1 = *(const float4*)(sp + 4);
        size_t base = (size_t)t * 32768 + ((size_t)oct * 32 + b) * 8;
        *(float4*)(XTF + base) = f0;
        *(float4*)(XTF + base + 4) = f1;
        u32x4 hi = {pkhi(f0.x, f0.y), pkhi(f0.z, f0.w), pkhi(f1.x, f1.y), pkhi(f1.z, f1.w)};
        u32x4 lo = {pklo(f0.x, f0.y), pklo(f0.z, f0.w), pklo(f1.x, f1.y), pklo(f1.z, f1.w)};
        *(u32x4*)(XTH + base) = hi;
        *(u32x4*)(XTL + base) = lo;
    }
}

// ---------------- fp32 -> bf16 (RNE, projection A) ----------------
__global__ __launch_bounds__(256) void f32_to_bf16(const float* __restrict__ in,
                                                   unsigned short* __restrict__ out, int n) {
    int i = (blockIdx.x * 256 + threadIdx.x) * 8;
    if (i + 7 < n) {
        float4 f0 = *(const float4*)(in + i);
        float4 f1 = *(const float4*)(in + i + 4);
        bf16x8 v;
        v[0] = (short)f2bf(f0.x); v[1] = (short)f2bf(f0.y);
        v[2] = (short)f2bf(f0.z); v[3] = (short)f2bf(f0.w);
        v[4] = (short)f2bf(f1.x); v[5] = (short)f2bf(f1.y);
        v[6] = (short)f2bf(f1.z); v[7] = (short)f2bf(f1.w);
        *(bf16x8*)(out + i) = v;
    }
}

// ---------------- output projection (bf16 MFMA, 128x128 tile) ----------------
__global__ __launch_bounds__(256) void out_proj(const unsigned short* __restrict__ hsb,
                                                const float* __restrict__ emb,
                                                const float* __restrict__ fcb,
                                                float* __restrict__ out) {
    __shared__ unsigned short Al[128 * 40];
    __shared__ unsigned short Bl[128 * 40];
    int tid = threadIdx.x;
    int n0 = blockIdx.x * 128;
    int m0 = blockIdx.y * 128;
    int wid = tid >> 6, l = tid & 63;
    int wm = wid >> 1, wn = wid & 1;
    int c16 = l & 15, kg = l >> 4;

    f32x4 acc[4][4];
#pragma unroll
    for (int i = 0; i < 4; i++)
#pragma unroll
        for (int j = 0; j < 4; j++) acc[i][j] = (f32x4){0.f, 0.f, 0.f, 0.f};

    for (int k0 = 0; k0 < 1024; k0 += 32) {
#pragma unroll
        for (int i = 0; i < 2; i++) {
            int id = i * 256 + tid;
            int r = id >> 2, ccc = id & 3;
            *(bf16x8*)&Al[r * 40 + ccc * 8] =
                *(const bf16x8*)(hsb + (size_t)(m0 + r) * 1024 + k0 + ccc * 8);
        }
#pragma unroll
        for (int i = 0; i < 2; i++) {
            int id = i * 256 + tid;
            int r = id >> 2, ccc = id & 3;
            const float* src = emb + (size_t)(n0 + r) * 1024 + k0 + ccc * 8;
            float4 f0 = *(const float4*)(src);
            float4 f1 = *(const float4*)(src + 4);
            bf16x8 v;
            v[0] = (short)f2bf(f0.x); v[1] = (short)f2bf(f0.y);
            v[2] = (short)f2bf(f0.z); v[3] = (short)f2bf(f0.w);
            v[4] = (short)f2bf(f1.x); v[5] = (short)f2bf(f1.y);
            v[6] = (short)f2bf(f1.z); v[7] = (short)f2bf(f1.w);
            *(bf16x8*)&Bl[r * 40 + ccc * 8] = v;
        }
        __syncthreads();

        bf16x8 afr[4], bfr[4];
#pragma unroll
        for (int i = 0; i < 4; i++)
            afr[i] = *(const bf16x8*)&Al[(wm * 64 + i * 16 + c16) * 40 + kg * 8];
#pragma unroll
        for (int j = 0; j < 4; j++)
            bfr[j] = *(const bf16x8*)&Bl[(wn * 64 + j * 16 + c16) * 40 + kg * 8];
#pragma unroll
        for (int i = 0; i < 4; i++)
#pragma unroll
            for (int j = 0; j < 4; j++)
                acc[i][j] = __builtin_amdgcn_mfma_f32_16x16x32_bf16(afr[i], bfr[j], acc[i][j], 0, 0, 0);
        __syncthreads();
    }

#pragma unroll
    for (int i = 0; i < 4; i++) {
        int row = m0 + wm * 64 + i * 16 + kg * 4;
#pragma unroll
        for (int j = 0; j < 4; j++) {
            int col = n0 + wn * 64 + j * 16 + c16;
            float fb = fcb[col];
#pragma unroll
            for (int r = 0; r < 4; r++)
                out[(size_t)(row + r) * 32000 + col] = acc[i][j][r] + fb;
        }
    }
}

// ---------------- host ----------------
extern "C" void kernel_launch(void* const* d_in, const int* in_sizes, int n_in,
                              void* d_out, int out_size, void* d_ws, size_t ws_size,
                              hipStream_t stream) {
    const int*   seq    = (const int*)d_in[0];
    const float* emb    = (const float*)d_in[2];
    const float* mog1_W = (const float*)d_in[3];
    const float* mog1_b = (const float*)d_in[4];
    const float* W_ih1  = (const float*)d_in[5];
    const float* W_hh1  = (const float*)d_in[6];
    const float* b_ih1  = (const float*)d_in[7];
    const float* b_hh1  = (const float*)d_in[8];
    const float* mog2_W = (const float*)d_in[9];
    const float* mog2_b = (const float*)d_in[10];
    const float* W_ih2  = (const float*)d_in[11];
    const float* W_hh2  = (const float*)d_in[12];
    const float* b_ih2  = (const float*)d_in[13];
    const float* b_hh2  = (const float*)d_in[14];
    const float* fc_b   = (const float*)d_in[15];

    char* ws = (char*)d_ws;
    float* XTF = (float*)ws;                                  // 8 MB
    u16*   XTH = (u16*)(ws + 8388608);                        // 4 MB
    u16*   XTL = (u16*)(ws + 12582912);                       // 4 MB
    float* stF = (float*)(ws + 16777216);                     // 1 MB
    u16*   stH = (u16*)(ws + 17825792);                       // 768 KB
    u32*   bar = (u32*)(ws + 18874368);                       // 32 KB (typed barrier lines + gen copies)
    unsigned short* hsb = (unsigned short*)(ws + 18907136);   // 4 MB

    float* out0 = (float*)d_out;
    float* hs   = out0 + 65536000LL;

    (void)hipMemsetAsync(stF, 0, 1835008, stream);
    (void)hipMemsetAsync(bar, 0, 32768, stream);

    gather_embed<<<64, 256, 0, stream>>>(seq, emb, XTF, XTH, XTL);

    RArgs a;
    a.m1W = mog1_W; a.m1b = mog1_b;
    a.Wih1 = W_ih1; a.Whh1 = W_hh1; a.bih1 = b_ih1; a.bhh1 = b_hh1;
    a.m2W = mog2_W; a.m2b = mog2_b;
    a.Wih2 = W_ih2; a.Whh2 = W_hh2; a.bih2 = b_ih2; a.bhh2 = b_hh2;
    a.XTF = XTF; a.XTH = XTH; a.XTL = XTL;
    a.stF = stF; a.stH = stH; a.hs = hs; a.bar = bar;

    reck<<<256, 256, 0, stream>>>(a);

    f32_to_bf16<<<1024, 256, 0, stream>>>(hs, hsb, 2097152);
    out_proj<<<dim3(250, 16), 256, 0, stream>>>(hsb, emb, fc_b, out0);
}

// Round 14
// 4229.971 us; speedup vs baseline: 1.0482x; 1.0473x over previous
//
#include <hip/hip_runtime.h>

typedef short bf16x8 __attribute__((ext_vector_type(8)));
typedef float f32x4 __attribute__((ext_vector_type(4)));
typedef unsigned int u32;
typedef u32 u32x4 __attribute__((ext_vector_type(4)));
typedef unsigned short u16;
typedef unsigned long long u64;

static __device__ __forceinline__ unsigned short f2bf(float f) {
    unsigned int u = __float_as_uint(f);
    unsigned int r = (u + 0x7fffu + ((u >> 16) & 1u)) >> 16;
    return (unsigned short)r;
}
static __device__ __forceinline__ float sigmoidf_(float x) {
    return 1.0f / (1.0f + __expf(-x));
}
static __device__ __forceinline__ float tanhf_(float x) {
    return 2.0f / (1.0f + __expf(-2.0f * x)) - 1.0f;
}

// truncation-split packing: fp32 -> (hi bf16, lo bf16)
static __device__ __forceinline__ u32 pkhi(float a, float b) {
    return (__float_as_uint(a) >> 16) | (__float_as_uint(b) & 0xffff0000u);
}
static __device__ __forceinline__ u32 pklo(float a, float b) {
    float la = a - __uint_as_float(__float_as_uint(a) & 0xffff0000u);
    float lb = b - __uint_as_float(__float_as_uint(b) & 0xffff0000u);
    return (__float_as_uint(la) >> 16) | (__float_as_uint(lb) & 0xffff0000u);
}
static __device__ __forceinline__ bf16x8 mkfrag(u32 a, u32 b, u32 c, u32 d) {
    u32x4 v = {a, b, c, d};
    return __builtin_bit_cast(bf16x8, v);
}

// ---- sc1 coherent activation access (fence-free scheme, proven R5+) ----
static __device__ __forceinline__ bf16x8 ldA(const u16* p) {
    u64 a = __hip_atomic_load((const u64*)p, __ATOMIC_RELAXED, __HIP_MEMORY_SCOPE_AGENT);
    u64 b = __hip_atomic_load((const u64*)(p + 4), __ATOMIC_RELAXED, __HIP_MEMORY_SCOPE_AGENT);
    union { u64 q[2]; bf16x8 v; } u;
    u.q[0] = a; u.q[1] = b;
    return u.v;
}
static __device__ __forceinline__ float ldc4(const float* p) {
    return __hip_atomic_load(p, __ATOMIC_RELAXED, __HIP_MEMORY_SCOPE_AGENT);
}
static __device__ __forceinline__ void stc4(float* p, float v) {
    __hip_atomic_store(p, v, __ATOMIC_RELAXED, __HIP_MEMORY_SCOPE_AGENT);
}
static __device__ __forceinline__ void stc2(u16* p, u16 v) {
    __hip_atomic_store(p, v, __ATOMIC_RELAXED, __HIP_MEMORY_SCOPE_AGENT);
}

static __device__ __forceinline__ void dma16(const float* g, float* l) {
    __builtin_amdgcn_global_load_lds((const __attribute__((address_space(1))) void*)g,
                                     (__attribute__((address_space(3))) void*)l, 16, 0, 0);
}

// ---------------- typed barriers with fanned-out release ----------------
// bar (u32 idx): moglines (layer*32+i)*32, i<32 -> [0,2048)   (ONLY mog arrivals)
//                g6lines 2048 + j*32, j<64       -> [2048,4096) (ONLY g6 arrivals)
//                genM[layer]: 16 copies at 4096 + layer*512 + c*32   (c<16)
//                genG[layer]: 16 copies at 5120 + layer*512 + c*32
static __device__ __forceinline__ void lineAdd(u32* bar, int idx, u32 v) {
    __hip_atomic_fetch_add(bar + idx, v, __ATOMIC_RELAXED, __HIP_MEMORY_SCOPE_AGENT);
}
static __device__ __forceinline__ u32 lsum(u32* bar, int baseIdx, int nl) {
    u32 v = 0;
    if ((int)threadIdx.x < nl)
        v = __hip_atomic_load(bar + baseIdx + (int)threadIdx.x * 32,
                              __ATOMIC_RELAXED, __HIP_MEMORY_SCOPE_AGENT);
    v += __shfl_xor(v, 1);
    v += __shfl_xor(v, 2);
    v += __shfl_xor(v, 4);
    v += __shfl_xor(v, 8);
    v += __shfl_xor(v, 16);
    v += __shfl_xor(v, 32);
    return v;
}
static __device__ __forceinline__ void genRelease(u32* bar, int genIdx, u32 t) {
    if (threadIdx.x < 16)
        __hip_atomic_store(bar + genIdx + (int)threadIdx.x * 32, t,
                           __ATOMIC_RELAXED, __HIP_MEMORY_SCOPE_AGENT);
}
// master: detect sum over lines, release 16 gen copies; others: poll own copy.
static __device__ __forceinline__ void waitGen(u32* bar, int lineBase, int nl, int genIdx,
                                               bool master, u32 t, u32 need, int myc) {
    if (master) {
        if (threadIdx.x < 64) {
            for (;;) {
                u32 v = lsum(bar, lineBase, nl);
                if (v >= need) break;
                __builtin_amdgcn_s_sleep(1);
            }
            genRelease(bar, genIdx, t);
        }
    } else {
        if (threadIdx.x == 0) {
            while (__hip_atomic_load(bar + genIdx + myc * 32, __ATOMIC_RELAXED,
                                     __HIP_MEMORY_SCOPE_AGENT) < t)
                __builtin_amdgcn_s_sleep(1);
        }
    }
    __builtin_amdgcn_s_barrier();
    asm volatile("" ::: "memory");
}

// ---------------- weight staging (self-staged: wave stages exactly what it reads) -----
// mog: 16 rows x 1024 k fp32 = 64KB; LDS float idx = oct*128 + row*8 + half*4.
static __device__ __forceinline__ void stage_mogF(const float* W, int jb, float* lbuf,
                                                  int lane, int wv) {
    int oct2 = lane >> 5, row = (lane >> 1) & 15, half = lane & 1;
#pragma unroll
    for (int i = 0; i < 16; ++i) {
        int og = wv * 16 + i;
        const float* src = W + (size_t)(jb + row) * 1024 + (og * 2 + oct2) * 8 + half * 4;
        dma16(src, lbuf + og * 256);
    }
}
// lstm chunk: 64 rows x 128 k = 32KB; idx = octl*512 + rowc*8 + half*4.
static __device__ __forceinline__ void stage_l128(const float* Ws, int jb, int kb,
                                                  float* lbuf, int lane, int wv) {
    int half = lane & 1;
#pragma unroll
    for (int i = 0; i < 8; ++i) {
        int octl = wv * 4 + (i >> 1);
        int rh = i & 1;
        int rowc = rh * 32 + (lane >> 1);
        int grow = (rowc >> 4) * 1024 + jb + (rowc & 15);
        const float* src = Ws + (size_t)grow * 1024 + kb + octl * 8 + half * 4;
        dma16(src, lbuf + octl * 512 + rh * 256);
    }
}

// ---------------- lstm chunk pieces ----------------
static __device__ __forceinline__ void l_acts(const u16* aH, const u16* aL, int cidx,
                                              int lane, int wv, bf16x8 fr[4]) {
    const int col = lane & 15, kq4 = lane >> 4;
    size_t octa = (size_t)cidx * 16 + wv * 4 + kq4;
    const u16* pH = aH + (octa * 32 + col) * 8;
    const u16* pL = aL + (octa * 32 + col) * 8;
    fr[0] = ldA(pH);
    fr[1] = ldA(pH + 128);
    fr[2] = ldA(pL);
    fr[3] = ldA(pL + 128);
}
static __device__ __forceinline__ void l_mfma(const float* lbuf, const bf16x8 fr[4],
                                              int lane, int wv, f32x4 (&acc)[4][2]) {
    const int col = lane & 15, kq4 = lane >> 4;
    const float* wbase = lbuf + (wv * 4 + kq4) * 512;
#pragma unroll
    for (int rt = 0; rt < 4; ++rt) {
        const float* wp = wbase + (rt * 16 + col) * 8;
        f32x4 w0 = *(const f32x4*)wp, w1 = *(const f32x4*)(wp + 4);
        bf16x8 whi = mkfrag(pkhi(w0.x, w0.y), pkhi(w0.z, w0.w),
                            pkhi(w1.x, w1.y), pkhi(w1.z, w1.w));
        bf16x8 wlo = mkfrag(pklo(w0.x, w0.y), pklo(w0.z, w0.w),
                            pklo(w1.x, w1.y), pklo(w1.z, w1.w));
        acc[rt][0] = __builtin_amdgcn_mfma_f32_16x16x32_bf16(fr[0], whi, acc[rt][0], 0, 0, 0);
        acc[rt][0] = __builtin_amdgcn_mfma_f32_16x16x32_bf16(fr[2], whi, acc[rt][0], 0, 0, 0);
        acc[rt][0] = __builtin_amdgcn_mfma_f32_16x16x32_bf16(fr[0], wlo, acc[rt][0], 0, 0, 0);
        acc[rt][1] = __builtin_amdgcn_mfma_f32_16x16x32_bf16(fr[1], whi, acc[rt][1], 0, 0, 0);
        acc[rt][1] = __builtin_amdgcn_mfma_f32_16x16x32_bf16(fr[3], whi, acc[rt][1], 0, 0, 0);
        acc[rt][1] = __builtin_amdgcn_mfma_f32_16x16x32_bf16(fr[1], wlo, acc[rt][1], 0, 0, 0);
    }
}

// ---------------- persistent recurrence kernel ----------------
struct RArgs {
    const float *m1W, *m1b, *Wih1, *Whh1, *bih1, *bhh1;
    const float *m2W, *m2b, *Wih2, *Whh2, *bih2, *bhh2;
    float* XTF;
    u16 *XTH, *XTL;
    float* stF;
    u16* stH;
    float* hs;
    u32* bar;
};

__global__ __launch_bounds__(256, 1) void reck(RArgs A) {
    __shared__ float wbuf[4][8192];   // 4 x 32KB (mog: 2 x 64KB)
    __shared__ float red[4][32][16];  // 8KB

    const int tid = threadIdx.x, lane = tid & 63, wv = tid >> 6;
    const int col = lane & 15, kq4 = lane >> 4;
    const int blk = blockIdx.x;
    const int layer = blk >> 7;
    const int g = blk & 127;
    const bool isMog = g < 64;
    const bool masterM = (g == 0);
    const bool masterG = (g == 64);
    const int moglineIdx = layer * 1024 + (g & 31) * 32;
    const int g6lineIdx  = 2048 + (blk & 63) * 32;
    const int genMi = 4096 + layer * 512;
    const int genGi = 5120 + layer * 512;
    const int myc = blk & 15;
    const int jb = (g & 63) * 16;

    const float* mW  = layer ? A.m2W : A.m1W;
    const float* mb_ = layer ? A.m2b : A.m1b;
    const float* Wih = layer ? A.Wih2 : A.Wih1;
    const float* Whh = layer ? A.Whh2 : A.Whh1;
    const float* bih = layer ? A.bih2 : A.bih1;
    const float* bhh = layer ? A.bhh2 : A.bhh1;

    float* hF  = A.stF + layer * 32768;
    float* hmF = A.stF + 65536 + layer * 32768;
    float* cS  = A.stF + 131072 + layer * 32768;
    float* rFb = A.stF + 196608;
    u16* hH  = A.stH + layer * 32768;
    u16* hmH = A.stH + 65536 + layer * 32768;
    u16* rHb = A.stH + 131072;
    u16* hL  = A.stH + 196608 + layer * 32768;
    u16* hmL = A.stH + 262144 + layer * 32768;
    u16* rLb = A.stH + 327680;

    float* mbuf0 = &wbuf[0][0];
    float* mbuf1 = &wbuf[2][0];

    u32 mgbase = 0;
    int cur = 0;

    if (isMog) {
        stage_mogF(mW, jb, mbuf0, lane, wv);   // prologue: ph0 weights
        asm volatile("s_waitcnt vmcnt(0)" ::: "memory");
    }
    __builtin_amdgcn_s_barrier();

    for (int s = 0; s <= 64; ++s) {
        const bool act = layer ? (s > 0) : (s < 64);
        const int t = layer ? s - 1 : s;
        const int tt = act ? t : 0;
        const int rb = tt & 1;

        float* xF; u16 *xH, *xL;
        if (layer == 0) {
            xF = A.XTF + (size_t)tt * 32768;
            xH = A.XTH + (size_t)tt * 32768;
            xL = A.XTL + (size_t)tt * 32768;
        } else {
            xF = rFb + rb * 32768;
            xH = rHb + rb * 32768;
            xL = rLb + rb * 32768;
        }

        if (isMog) {
            if (act) {
                for (int ph = 0; ph < 5; ++ph) {
                    float* wsrc = cur ? mbuf1 : mbuf0;
                    float* wdst = cur ? mbuf0 : mbuf1;
                    const u16 *gH, *gL; const float* srcF; float* dF; u16 *dH, *dL;
                    switch (ph) {
                        case 0:  gH = hH;  gL = hL;  srcF = xF;  dF = xF;  dH = xH;  dL = xL;  break;
                        case 1:  gH = xH;  gL = xL;  srcF = hF;  dF = hmF; dH = hmH; dL = hmL; break;
                        case 2:  gH = hmH; gL = hmL; srcF = xF;  dF = xF;  dH = xH;  dL = xL;  break;
                        case 3:  gH = xH;  gL = xL;  srcF = hmF; dF = hmF; dH = hmH; dL = hmL; break;
                        default: gH = hmH; gL = hmL; srcF = xF;  dF = xF;  dH = xH;  dL = xL;  break;
                    }
                    // acts first (64 loads/wave), then srcF prefetch (2 loads)
                    bf16x8 AH0[8], AH1[8], AL0[8], AL1[8];
#pragma unroll
                    for (int kt = 0; kt < 8; ++kt) {
                        int octc = wv * 32 + kt * 4 + kq4;
                        const u16* pH = gH + ((size_t)octc * 32 + col) * 8;
                        const u16* pL = gL + ((size_t)octc * 32 + col) * 8;
                        AH0[kt] = ldA(pH);  AH1[kt] = ldA(pH + 128);
                        AL0[kt] = ldA(pL);  AL1[kt] = ldA(pL + 128);
                    }
                    float sF[2];
                    size_t pidxv[2];
#pragma unroll
                    for (int uu = 0; uu < 2; ++uu) {
                        int u = tid + uu * 256;
                        int jj = u & 15, bb = u >> 4;
                        int d = jb + jj;
                        pidxv[uu] = ((size_t)(d >> 3) * 32 + bb) * 8 + (d & 7);
                        sF[uu] = ldc4(srcF + pidxv[uu]);
                    }
                    // drain prev-phase stage (16 oldest; vmcnt 6-bit max 63); acts keep flying
                    asm volatile("s_waitcnt vmcnt(63)" ::: "memory");
                    f32x4 a0 = {0.f, 0.f, 0.f, 0.f}, a1 = {0.f, 0.f, 0.f, 0.f};
#pragma unroll
                    for (int kt = 0; kt < 8; ++kt) {
                        int octc = wv * 32 + kt * 4 + kq4;
                        const float* wp = wsrc + octc * 128 + col * 8;
                        f32x4 w0 = *(const f32x4*)wp, w1 = *(const f32x4*)(wp + 4);
                        bf16x8 whi = mkfrag(pkhi(w0.x, w0.y), pkhi(w0.z, w0.w),
                                            pkhi(w1.x, w1.y), pkhi(w1.z, w1.w));
                        bf16x8 wlo = mkfrag(pklo(w0.x, w0.y), pklo(w0.z, w0.w),
                                            pklo(w1.x, w1.y), pklo(w1.z, w1.w));
                        a0 = __builtin_amdgcn_mfma_f32_16x16x32_bf16(AH0[kt], whi, a0, 0, 0, 0);
                        a0 = __builtin_amdgcn_mfma_f32_16x16x32_bf16(AL0[kt], whi, a0, 0, 0, 0);
                        a0 = __builtin_amdgcn_mfma_f32_16x16x32_bf16(AH0[kt], wlo, a0, 0, 0, 0);
                        a1 = __builtin_amdgcn_mfma_f32_16x16x32_bf16(AH1[kt], whi, a1, 0, 0, 0);
                        a1 = __builtin_amdgcn_mfma_f32_16x16x32_bf16(AL1[kt], whi, a1, 0, 0, 0);
                        a1 = __builtin_amdgcn_mfma_f32_16x16x32_bf16(AH1[kt], wlo, a1, 0, 0, 0);
                    }
#pragma unroll
                    for (int mh = 0; mh < 2; ++mh) {
                        f32x4 av = mh ? a1 : a0;
#pragma unroll
                        for (int r = 0; r < 4; ++r)
                            red[wv][mh * 16 + kq4 * 4 + r][col] = av[r];
                    }
                    __syncthreads();
#pragma unroll
                    for (int uu = 0; uu < 2; ++uu) {
                        int u = tid + uu * 256;
                        int jj = u & 15, bb = u >> 4;
                        float sv = red[0][bb][jj] + red[1][bb][jj]
                                 + red[2][bb][jj] + red[3][bb][jj];
                        int d = jb + jj;
                        sv += mb_[ph * 1024 + d];
                        float gate = 2.0f * sigmoidf_(sv);
                        float val = gate * sF[uu];
                        stc4(dF + pidxv[uu], val);
                        u32 uv = __float_as_uint(val);
                        stc2(dH + pidxv[uu], (u16)(uv >> 16));
                        float lov = val - __uint_as_float(uv & 0xffff0000u);
                        stc2(dL + pidxv[uu], (u16)(__float_as_uint(lov) >> 16));
                    }
                    // draining arrive: only the 6 sc1 stores are in flight here (~fast)
                    asm volatile("s_waitcnt vmcnt(0) lgkmcnt(0)" ::: "memory");
                    __builtin_amdgcn_s_barrier();
                    if (tid == 0) lineAdd(A.bar, moglineIdx, 1);
                    // stage AFTER the arrival add: flies through barrier wait + next acts
                    stage_mogF(mW + (size_t)((ph + 1) % 5) * 1048576, jb, wdst, lane, wv);
                    if (ph < 4)
                        waitGen(A.bar, layer * 1024, 32, genMi, masterM,
                                mgbase + ph + 1, (mgbase + ph + 1) << 6, myc);
                    cur ^= 1;
                }
                // master releases b5 for lstm (no wait for other mog blocks)
                if (masterM) {
                    if (tid < 64) {
                        for (;;) {
                            u32 v = lsum(A.bar, layer * 1024, 32);
                            if (v >= ((mgbase + 5) << 6)) break;
                            __builtin_amdgcn_s_sleep(1);
                        }
                        genRelease(A.bar, genMi, mgbase + 5);
                    }
                }
                __builtin_amdgcn_s_barrier();
                if (tid == 0) lineAdd(A.bar, g6lineIdx, 1);
            } else {
                __builtin_amdgcn_s_barrier();
                if (tid == 0) {
                    lineAdd(A.bar, moglineIdx, 5);   // keep counts homogeneous
                    lineAdd(A.bar, g6lineIdx, 1);
                }
            }
            waitGen(A.bar, 2048, 64, genGi, false, (u32)(s + 1), (u32)(s + 1) << 8, myc);
        } else {
            // ---------- LSTM block ----------
            if (act) {
                const bool firstAct = layer ? (s == 1) : (s == 0);
                const bool nextAct = layer ? (s < 64) : (s < 63);
                if (firstAct) {
#pragma unroll
                    for (int c = 0; c < 3; ++c)
                        stage_l128(Whh, jb, c * 128, &wbuf[c][0], lane, wv);
                }
                // single wait: hm final (end of ph3)
                waitGen(A.bar, layer * 1024, 32, genMi, false, mgbase + 4, 0, myc);
                f32x4 acc[4][2];
#pragma unroll
                for (int rt = 0; rt < 4; ++rt) {
                    acc[rt][0] = (f32x4){0.f, 0.f, 0.f, 0.f};
                    acc[rt][1] = (f32x4){0.f, 0.f, 0.f, 0.f};
                }
                bf16x8 frA[4], frB[4];
                l_acts(hmH, hmL, 0, lane, wv, frA);
#pragma unroll
                for (int c = 0; c < 8; ++c) {         // Whh side (overlaps mog ph4)
                    if (c < 7) {
                        if (c & 1) l_acts(hmH, hmL, c + 1, lane, wv, frA);
                        else       l_acts(hmH, hmL, c + 1, lane, wv, frB);
                    }
                    asm volatile("s_waitcnt vmcnt(32)" ::: "memory");
                    int cn = c + 3;
                    if (cn < 8) stage_l128(Whh, jb, cn * 128, &wbuf[cn & 3][0], lane, wv);
                    else        stage_l128(Wih, jb, (cn - 8) * 128, &wbuf[cn & 3][0], lane, wv);
                    if (c & 1) l_mfma(&wbuf[c & 3][0], frB, lane, wv, acc);
                    else       l_mfma(&wbuf[c & 3][0], frA, lane, wv, acc);
                }
                // x ready (end of ph4)
                waitGen(A.bar, layer * 1024, 32, genMi, false, mgbase + 5, 0, myc);
                l_acts(xH, xL, 0, lane, wv, frA);
#pragma unroll
                for (int c = 0; c < 8; ++c) {         // Wih side
                    if (c < 7) {
                        if (c & 1) l_acts(xH, xL, c + 1, lane, wv, frA);
                        else       l_acts(xH, xL, c + 1, lane, wv, frB);
                    }
                    asm volatile("s_waitcnt vmcnt(32)" ::: "memory");
                    int cn = c + 3;
                    if (cn < 8) stage_l128(Wih, jb, cn * 128, &wbuf[cn & 3][0], lane, wv);
                    if (c & 1) l_mfma(&wbuf[c & 3][0], frB, lane, wv, acc);
                    else       l_mfma(&wbuf[c & 3][0], frA, lane, wv, acc);
                }
                // cross-wave K reduction, gates, state update
                float gv[2][4];
#pragma unroll
                for (int gt = 0; gt < 4; ++gt) {
                    __syncthreads();
#pragma unroll
                    for (int mh = 0; mh < 2; ++mh) {
                        f32x4 av = acc[gt][mh];
#pragma unroll
                        for (int r = 0; r < 4; ++r)
                            red[wv][mh * 16 + kq4 * 4 + r][col] = av[r];
                    }
                    __syncthreads();
#pragma unroll
                    for (int uu = 0; uu < 2; ++uu) {
                        int u = tid + uu * 256;
                        gv[uu][gt] = red[0][u >> 4][u & 15] + red[1][u >> 4][u & 15]
                                   + red[2][u >> 4][u & 15] + red[3][u >> 4][u & 15];
                    }
                }
#pragma unroll
                for (int uu = 0; uu < 2; ++uu) {
                    int u = tid + uu * 256;
                    int cell = u & 15, bb = u >> 4;
                    int d = jb + cell;
                    float gi = gv[uu][0] + bih[d] + bhh[d];
                    float gf = gv[uu][1] + bih[1024 + d] + bhh[1024 + d];
                    float gg = gv[uu][2] + bih[2048 + d] + bhh[2048 + d];
                    float go = gv[uu][3] + bih[3072 + d] + bhh[3072 + d];
                    int cidx = d * 32 + bb;
                    float cn = sigmoidf_(gf) * cS[cidx] + sigmoidf_(gi) * tanhf_(gg);
                    cS[cidx] = cn;
                    float hn = sigmoidf_(go) * tanhf_(cn);
                    size_t pidx = ((size_t)(d >> 3) * 32 + bb) * 8 + (d & 7);
                    u32 uv = __float_as_uint(hn);
                    u16 hhi = (u16)(uv >> 16);
                    float lov = hn - __uint_as_float(uv & 0xffff0000u);
                    u16 hlo = (u16)(__float_as_uint(lov) >> 16);
                    stc4(hF + pidx, hn);
                    stc2(hH + pidx, hhi);
                    stc2(hL + pidx, hlo);
                    if (layer == 0) {
                        int wb = s & 1;
                        stc4(rFb + wb * 32768 + pidx, hn);
                        stc2(rHb + wb * 32768 + pidx, hhi);
                        stc2(rLb + wb * 32768 + pidx, hlo);
                    } else {
                        A.hs[(size_t)bb * 65536 + (size_t)t * 1024 + d] = hn;
                    }
                }
                // g6 arrival: publish h, then count
                asm volatile("s_waitcnt vmcnt(0) lgkmcnt(0)" ::: "memory");
                __builtin_amdgcn_s_barrier();
                if (tid == 0) lineAdd(A.bar, g6lineIdx, 1);
                if (nextAct) {                        // next-slot Whh c0..c2 fly through g6
#pragma unroll
                    for (int c = 0; c < 3; ++c)
                        stage_l128(Whh, jb, c * 128, &wbuf[c][0], lane, wv);
                }
            } else {
                __builtin_amdgcn_s_barrier();
                if (tid == 0) lineAdd(A.bar, g6lineIdx, 1);
            }
            waitGen(A.bar, 2048, 64, genGi, masterG, (u32)(s + 1), (u32)(s + 1) << 8, myc);
        }
        mgbase += 5;
    }
}

// ---------------- embedding gather into fp32 + hi/lo bf16 planes ----------------
__global__ __launch_bounds__(256) void gather_embed(const int* __restrict__ seq,
                                                    const float* __restrict__ emb,
                                                    float* __restrict__ XTF,
                                                    u16* __restrict__ XTH,
                                                    u16* __restrict__ XTL) {
    int t = blockIdx.x;
#pragma unroll 4
    for (int i = 0; i < 16; ++i) {
        int u = i * 256 + threadIdx.x;
        int oct = u >> 5, b = u & 31;
        int row = seq[b * 64 + t];
        const float* sp = emb + (size_t)row * 1024 + oct * 8;
        float4 f0 = *(const float4*)sp;
        float4 f1 = *(const float4*)(sp + 4);
        size_t base = (size_t)t * 32768 + ((size_t)oct * 32 + b) * 8;
        *(float4*)(XTF + base) = f0;
        *(float4*)(XTF + base + 4) = f1;
        u32x4 hi = {pkhi(f0.x, f0.y), pkhi(f0.z, f0.w), pkhi(f1.x, f1.y), pkhi(f1.z, f1.w)};
        u32x4 lo = {pklo(f0.x, f0.y), pklo(f0.z, f0.w), pklo(f1.x, f1.y), pklo(f1.z, f1.w)};
        *(u32x4*)(XTH + base) = hi;
        *(u32x4*)(XTL + base) = lo;
    }
}

// ---------------- fp32 -> bf16 (RNE, projection A) ----------------
__global__ __launch_bounds__(256) void f32_to_bf16(const float* __restrict__ in,
                                                   unsigned short* __restrict__ out, int n) {
    int i = (blockIdx.x * 256 + threadIdx.x) * 8;
    if (i + 7 < n) {
        float4 f0 = *(const float4*)(in + i);
        float4 f1 = *(const float4*)(in + i + 4);
        bf16x8 v;
        v[0] = (short)f2bf(f0.x); v[1] = (short)f2bf(f0.y);
        v[2] = (short)f2bf(f0.z); v[3] = (short)f2bf(f0.w);
        v[4] = (short)f2bf(f1.x); v[5] = (short)f2bf(f1.y);
        v[6] = (short)f2bf(f1.z); v[7] = (short)f2bf(f1.w);
        *(bf16x8*)(out + i) = v;
    }
}

// ---------------- output projection (bf16 MFMA, 128x128 tile) ----------------
__global__ __launch_bounds__(256) void out_proj(const unsigned short* __restrict__ hsb,
                                                const float* __restrict__ emb,
                                                const float* __restrict__ fcb,
                                                float* __restrict__ out) {
    __shared__ unsigned short Al[128 * 40];
    __shared__ unsigned short Bl[128 * 40];
    int tid = threadIdx.x;
    int n0 = blockIdx.x * 128;
    int m0 = blockIdx.y * 128;
    int wid = tid >> 6, l = tid & 63;
    int wm = wid >> 1, wn = wid & 1;
    int c16 = l & 15, kg = l >> 4;

    f32x4 acc[4][4];
#pragma unroll
    for (int i = 0; i < 4; i++)
#pragma unroll
        for (int j = 0; j < 4; j++) acc[i][j] = (f32x4){0.f, 0.f, 0.f, 0.f};

    for (int k0 = 0; k0 < 1024; k0 += 32) {
#pragma unroll
        for (int i = 0; i < 2; i++) {
            int id = i * 256 + tid;
            int r = id >> 2, ccc = id & 3;
            *(bf16x8*)&Al[r * 40 + ccc * 8] =
                *(const bf16x8*)(hsb + (size_t)(m0 + r) * 1024 + k0 + ccc * 8);
        }
#pragma unroll
        for (int i = 0; i < 2; i++) {
            int id = i * 256 + tid;
            int r = id >> 2, ccc = id & 3;
            const float* src = emb + (size_t)(n0 + r) * 1024 + k0 + ccc * 8;
            float4 f0 = *(const float4*)(src);
            float4 f1 = *(const float4*)(src + 4);
            bf16x8 v;
            v[0] = (short)f2bf(f0.x); v[1] = (short)f2bf(f0.y);
            v[2] = (short)f2bf(f0.z); v[3] = (short)f2bf(f0.w);
            v[4] = (short)f2bf(f1.x); v[5] = (short)f2bf(f1.y);
            v[6] = (short)f2bf(f1.z); v[7] = (short)f2bf(f1.w);
            *(bf16x8*)&Bl[r * 40 + ccc * 8] = v;
        }
        __syncthreads();

        bf16x8 afr[4], bfr[4];
#pragma unroll
        for (int i = 0; i < 4; i++)
            afr[i] = *(const bf16x8*)&Al[(wm * 64 + i * 16 + c16) * 40 + kg * 8];
#pragma unroll
        for (int j = 0; j < 4; j++)
            bfr[j] = *(const bf16x8*)&Bl[(wn * 64 + j * 16 + c16) * 40 + kg * 8];
#pragma unroll
        for (int i = 0; i < 4; i++)
#pragma unroll
            for (int j = 0; j < 4; j++)
                acc[i][j] = __builtin_amdgcn_mfma_f32_16x16x32_bf16(afr[i], bfr[j], acc[i][j], 0, 0, 0);
        __syncthreads();
    }

#pragma unroll
    for (int i = 0; i < 4; i++) {
        int row = m0 + wm * 64 + i * 16 + kg * 4;
#pragma unroll
        for (int j = 0; j < 4; j++) {
            int col = n0 + wn * 64 + j * 16 + c16;
            float fb = fcb[col];
#pragma unroll
            for (int r = 0; r < 4; r++)
                out[(size_t)(row + r) * 32000 + col] = acc[i][j][r] + fb;
        }
    }
}

// ---------------- host ----------------
extern "C" void kernel_launch(void* const* d_in, const int* in_sizes, int n_in,
                              void* d_out, int out_size, void* d_ws, size_t ws_size,
                              hipStream_t stream) {
    const int*   seq    = (const int*)d_in[0];
    const float* emb    = (const float*)d_in[2];
    const float* mog1_W = (const float*)d_in[3];
    const float* mog1_b = (const float*)d_in[4];
    const float* W_ih1  = (const float*)d_in[5];
    const float* W_hh1  = (const float*)d_in[6];
    const float* b_ih1  = (const float*)d_in[7];
    const float* b_hh1  = (const float*)d_in[8];
    const float* mog2_W = (const float*)d_in[9];
    const float* mog2_b = (const float*)d_in[10];
    const float* W_ih2  = (const float*)d_in[11];
    const float* W_hh2  = (const float*)d_in[12];
    const float* b_ih2  = (const float*)d_in[13];
    const float* b_hh2  = (const float*)d_in[14];
    const float* fc_b   = (const float*)d_in[15];

    char* ws = (char*)d_ws;
    float* XTF = (float*)ws;                                  // 8 MB
    u16*   XTH = (u16*)(ws + 8388608);                        // 4 MB
    u16*   XTL = (u16*)(ws + 12582912);                       // 4 MB
    float* stF = (float*)(ws + 16777216);                     // 1 MB
    u16*   stH = (u16*)(ws + 17825792);                       // 768 KB
    u32*   bar = (u32*)(ws + 18874368);                       // 32 KB
    unsigned short* hsb = (unsigned short*)(ws + 18907136);   // 4 MB

    float* out0 = (float*)d_out;
    float* hs   = out0 + 65536000LL;

    (void)hipMemsetAsync(stF, 0, 1835008, stream);
    (void)hipMemsetAsync(bar, 0, 32768, stream);

    gather_embed<<<64, 256, 0, stream>>>(seq, emb, XTF, XTH, XTL);

    RArgs a;
    a.m1W = mog1_W; a.m1b = mog1_b;
    a.Wih1 = W_ih1; a.Whh1 = W_hh1; a.bih1 = b_ih1; a.bhh1 = b_hh1;
    a.m2W = mog2_W; a.m2b = mog2_b;
    a.Wih2 = W_ih2; a.Whh2 = W_hh2; a.bih2 = b_ih2; a.bhh2 = b_hh2;
    a.XTF = XTF; a.XTH = XTH; a.XTL = XTL;
    a.stF = stF; a.stH = stH; a.hs = hs; a.bar = bar;

    reck<<<256, 256, 0, stream>>>(a);

    f32_to_bf16<<<1024, 256, 0, stream>>>(hs, hsb, 2097152);
    out_proj<<<dim3(250, 16), 256, 0, stream>>>(hsb, emb, fc_b, out0);
}

// Round 15
// 3849.515 us; speedup vs baseline: 1.1518x; 1.0988x over previous
//
#include <hip/hip_runtime.h>

typedef short bf16x8 __attribute__((ext_vector_type(8)));
typedef float f32x4 __attribute__((ext_vector_type(4)));
typedef unsigned int u32;
typedef u32 u32x4 __attribute__((ext_vector_type(4)));
typedef unsigned short u16;
typedef unsigned long long u64;

static __device__ __forceinline__ unsigned short f2bf(float f) {
    unsigned int u = __float_as_uint(f);
    unsigned int r = (u + 0x7fffu + ((u >> 16) & 1u)) >> 16;
    return (unsigned short)r;
}
static __device__ __forceinline__ float sigmoidf_(float x) {
    return 1.0f / (1.0f + __expf(-x));
}
static __device__ __forceinline__ float tanhf_(float x) {
    return 2.0f / (1.0f + __expf(-2.0f * x)) - 1.0f;
}

// truncation-split packing: fp32 -> (hi bf16, lo bf16)
static __device__ __forceinline__ u32 pkhi(float a, float b) {
    return (__float_as_uint(a) >> 16) | (__float_as_uint(b) & 0xffff0000u);
}
static __device__ __forceinline__ u32 pklo(float a, float b) {
    float la = a - __uint_as_float(__float_as_uint(a) & 0xffff0000u);
    float lb = b - __uint_as_float(__float_as_uint(b) & 0xffff0000u);
    return (__float_as_uint(la) >> 16) | (__float_as_uint(lb) & 0xffff0000u);
}
static __device__ __forceinline__ bf16x8 mkfrag(u32 a, u32 b, u32 c, u32 d) {
    u32x4 v = {a, b, c, d};
    return __builtin_bit_cast(bf16x8, v);
}

// ---- sc1 coherent activation access (fence-free scheme) ----
static __device__ __forceinline__ bf16x8 ldA(const u16* p) {
    u64 a = __hip_atomic_load((const u64*)p, __ATOMIC_RELAXED, __HIP_MEMORY_SCOPE_AGENT);
    u64 b = __hip_atomic_load((const u64*)(p + 4), __ATOMIC_RELAXED, __HIP_MEMORY_SCOPE_AGENT);
    union { u64 q[2]; bf16x8 v; } u;
    u.q[0] = a; u.q[1] = b;
    return u.v;
}
static __device__ __forceinline__ float ldc4(const float* p) {
    return __hip_atomic_load(p, __ATOMIC_RELAXED, __HIP_MEMORY_SCOPE_AGENT);
}
static __device__ __forceinline__ void stc4(float* p, float v) {
    __hip_atomic_store(p, v, __ATOMIC_RELAXED, __HIP_MEMORY_SCOPE_AGENT);
}
static __device__ __forceinline__ void stc2(u16* p, u16 v) {
    __hip_atomic_store(p, v, __ATOMIC_RELAXED, __HIP_MEMORY_SCOPE_AGENT);
}

static __device__ __forceinline__ void dma16(const float* g, float* l) {
    __builtin_amdgcn_global_load_lds((const __attribute__((address_space(1))) void*)g,
                                     (__attribute__((address_space(3))) void*)l, 16, 0, 0);
}

// ---------------- barriers ----------------
// bar layout (u32): arrival line i at bar[i*32], i=0..63 (layer0: 0-31, layer1: 32-63);
// gen[layer] at bar[2112 + layer*32]. Masters: block 0 (layer0), block 128 (layer1).
static __device__ __forceinline__ void arrA(u32* bar, int line) {   // active: publish stores
    asm volatile("s_waitcnt vmcnt(0) lgkmcnt(0)" ::: "memory");
    __builtin_amdgcn_s_barrier();
    if (threadIdx.x == 0)
        __hip_atomic_fetch_add(bar + line * 32, 1u, __ATOMIC_RELAXED, __HIP_MEMORY_SCOPE_AGENT);
}
static __device__ __forceinline__ void arrP(u32* bar, int line) {   // passive: stages keep flying
    __builtin_amdgcn_s_barrier();
    if (threadIdx.x == 0)
        __hip_atomic_fetch_add(bar + line * 32, 1u, __ATOMIC_RELAXED, __HIP_MEMORY_SCOPE_AGENT);
}
static __device__ __forceinline__ void bwait(u32* bar, int layer, bool master,
                                             bool glob, u32 target) {
    if (master) {
        if (threadIdx.x < 64) {
            const u32 tgt = glob ? (target << 8) : (target << 7);   // 256 or 128 arrivals
            int line = glob ? (int)threadIdx.x : layer * 32 + (int)(threadIdx.x & 31);
            bool on = glob || (threadIdx.x < 32);
            for (;;) {
                u32 v = on ? __hip_atomic_load(bar + line * 32, __ATOMIC_RELAXED,
                                               __HIP_MEMORY_SCOPE_AGENT) : 0u;
                v += __shfl_xor(v, 1);
                v += __shfl_xor(v, 2);
                v += __shfl_xor(v, 4);
                v += __shfl_xor(v, 8);
                v += __shfl_xor(v, 16);
                v += __shfl_xor(v, 32);
                if (v >= tgt) break;
                __builtin_amdgcn_s_sleep(1);
            }
            if (threadIdx.x == 0)
                __hip_atomic_store(bar + 2112 + layer * 32, target, __ATOMIC_RELAXED,
                                   __HIP_MEMORY_SCOPE_AGENT);
        }
    } else {
        if (threadIdx.x == 0) {
            while (__hip_atomic_load(bar + 2112 + layer * 32, __ATOMIC_RELAXED,
                                     __HIP_MEMORY_SCOPE_AGENT) < target)
                __builtin_amdgcn_s_sleep(1);
        }
    }
    __builtin_amdgcn_s_barrier();
    asm volatile("" ::: "memory");
}

// ---------------- weight staging (self-staged: wave stages exactly what it reads) -----
// mog: 16 rows x 1024 k fp32 = 64KB; LDS float idx = oct*128 + row*8 + half*4.
static __device__ __forceinline__ void stage_mogF(const float* W, int jb, float* lbuf,
                                                  int lane, int wv) {
    int oct2 = lane >> 5, row = (lane >> 1) & 15, half = lane & 1;
#pragma unroll
    for (int i = 0; i < 16; ++i) {
        int og = wv * 16 + i;
        const float* src = W + (size_t)(jb + row) * 1024 + (og * 2 + oct2) * 8 + half * 4;
        dma16(src, lbuf + og * 256);
    }
}
// lstm chunk: 64 rows (4 gates x 16 cells) x 128 k = 32KB; idx = octl*512 + rowc*8 + half*4.
static __device__ __forceinline__ void stage_l128(const float* Ws, int jb, int kb,
                                                  float* lbuf, int lane, int wv) {
    int half = lane & 1;
#pragma unroll
    for (int i = 0; i < 8; ++i) {
        int octl = wv * 4 + (i >> 1);
        int rh = i & 1;
        int rowc = rh * 32 + (lane >> 1);
        int grow = (rowc >> 4) * 1024 + jb + (rowc & 15);
        const float* src = Ws + (size_t)grow * 1024 + kb + octl * 8 + half * 4;
        dma16(src, lbuf + octl * 512 + rh * 256);
    }
}

// ---------------- lstm chunk pieces ----------------
static __device__ __forceinline__ void l_acts(const u16* aH, const u16* aL, int cidx,
                                              int lane, int wv, bf16x8 fr[4]) {
    const int col = lane & 15, kq4 = lane >> 4;
    size_t octa = (size_t)cidx * 16 + wv * 4 + kq4;
    const u16* pH = aH + (octa * 32 + col) * 8;
    const u16* pL = aL + (octa * 32 + col) * 8;
    fr[0] = ldA(pH);
    fr[1] = ldA(pH + 128);
    fr[2] = ldA(pL);
    fr[3] = ldA(pL + 128);
}
static __device__ __forceinline__ void l_mfma(const float* lbuf, const bf16x8 fr[4],
                                              int lane, int wv, f32x4 (&acc)[4][2]) {
    const int col = lane & 15, kq4 = lane >> 4;
    const float* wbase = lbuf + (wv * 4 + kq4) * 512;
#pragma unroll
    for (int rt = 0; rt < 4; ++rt) {
        const float* wp = wbase + (rt * 16 + col) * 8;
        f32x4 w0 = *(const f32x4*)wp, w1 = *(const f32x4*)(wp + 4);
        bf16x8 whi = mkfrag(pkhi(w0.x, w0.y), pkhi(w0.z, w0.w),
                            pkhi(w1.x, w1.y), pkhi(w1.z, w1.w));
        bf16x8 wlo = mkfrag(pklo(w0.x, w0.y), pklo(w0.z, w0.w),
                            pklo(w1.x, w1.y), pklo(w1.z, w1.w));
        acc[rt][0] = __builtin_amdgcn_mfma_f32_16x16x32_bf16(fr[0], whi, acc[rt][0], 0, 0, 0);
        acc[rt][0] = __builtin_amdgcn_mfma_f32_16x16x32_bf16(fr[2], whi, acc[rt][0], 0, 0, 0);
        acc[rt][0] = __builtin_amdgcn_mfma_f32_16x16x32_bf16(fr[0], wlo, acc[rt][0], 0, 0, 0);
        acc[rt][1] = __builtin_amdgcn_mfma_f32_16x16x32_bf16(fr[1], whi, acc[rt][1], 0, 0, 0);
        acc[rt][1] = __builtin_amdgcn_mfma_f32_16x16x32_bf16(fr[3], whi, acc[rt][1], 0, 0, 0);
        acc[rt][1] = __builtin_amdgcn_mfma_f32_16x16x32_bf16(fr[1], wlo, acc[rt][1], 0, 0, 0);
    }
}

// ---------------- persistent recurrence kernel ----------------
struct RArgs {
    const float *m1W, *m1b, *Wih1, *Whh1, *bih1, *bhh1;
    const float *m2W, *m2b, *Wih2, *Whh2, *bih2, *bhh2;
    float* XTF;
    u16 *XTH, *XTL;
    float* stF;
    u16* stH;
    float* hs;
    u32* bar;
};

__global__ __launch_bounds__(256, 1) void reck(RArgs A) {
    __shared__ float wbuf[4][8192];   // 4 x 32KB (mog: 2 x 64KB)
    __shared__ float red[4][32][16];  // 8KB

    const int tid = threadIdx.x, lane = tid & 63, wv = tid >> 6;
    const int col = lane & 15, kq4 = lane >> 4;
    const int blk = blockIdx.x;
    const int layer = blk >> 7;
    const int g = blk & 127;
    const bool isMog = g < 64;
    const bool master = (g == 0);
    const int line = layer * 32 + (g & 31);
    const int jb = (g & 63) * 16;

    const float* mW  = layer ? A.m2W : A.m1W;
    const float* mb_ = layer ? A.m2b : A.m1b;
    const float* Wih = layer ? A.Wih2 : A.Wih1;
    const float* Whh = layer ? A.Whh2 : A.Whh1;
    const float* bih = layer ? A.bih2 : A.bih1;
    const float* bhh = layer ? A.bhh2 : A.bhh1;

    float* hF  = A.stF + layer * 32768;
    float* hmF = A.stF + 65536 + layer * 32768;
    float* cS  = A.stF + 131072 + layer * 32768;
    float* rFb = A.stF + 196608;
    u16* hH  = A.stH + layer * 32768;
    u16* hmH = A.stH + 65536 + layer * 32768;
    u16* rHb = A.stH + 131072;
    u16* hL  = A.stH + 196608 + layer * 32768;
    u16* hmL = A.stH + 262144 + layer * 32768;
    u16* rLb = A.stH + 327680;

    float* mbuf0 = &wbuf[0][0];
    float* mbuf1 = &wbuf[2][0];

    u32 bcnt = 0;
    int cur = 0;

    if (isMog) stage_mogF(mW, jb, mbuf0, lane, wv);   // prologue: ph0 weights (16 dma/wave)

    for (int s = 0; s <= 64; ++s) {
        const bool act = layer ? (s > 0) : (s < 64);
        const int t = layer ? s - 1 : s;
        const int tt = act ? t : 0;
        const int rb = tt & 1;

        float* xF; u16 *xH, *xL;
        if (layer == 0) {
            xF = A.XTF + (size_t)tt * 32768;
            xH = A.XTH + (size_t)tt * 32768;
            xL = A.XTL + (size_t)tt * 32768;
        } else {
            xF = rFb + rb * 32768;
            xH = rHb + rb * 32768;
            xL = rLb + rb * 32768;
        }

        if (isMog) {
            for (int ph = 0; ph < 5; ++ph) {
                float* wsrc = cur ? mbuf1 : mbuf0;
                float* wdst = cur ? mbuf0 : mbuf1;
                if (act) {
                    const u16 *gH, *gL; const float* srcF; float* dF; u16 *dH, *dL;
                    switch (ph) {
                        case 0:  gH = hH;  gL = hL;  srcF = xF;  dF = xF;  dH = xH;  dL = xL;  break;
                        case 1:  gH = xH;  gL = xL;  srcF = hF;  dF = hmF; dH = hmH; dL = hmL; break;
                        case 2:  gH = hmH; gL = hmL; srcF = xF;  dF = xF;  dH = xH;  dL = xL;  break;
                        case 3:  gH = xH;  gL = xL;  srcF = hmF; dF = hmF; dH = hmH; dL = hmL; break;
                        default: gH = hmH; gL = hmL; srcF = xF;  dF = xF;  dH = xH;  dL = xL;  break;
                    }
                    // (1) act fragments up front — acts precede the stage in the vmcnt queue
                    bf16x8 AH0[8], AH1[8], AL0[8], AL1[8];
#pragma unroll
                    for (int kt = 0; kt < 8; ++kt) {
                        int octc = wv * 32 + kt * 4 + kq4;
                        const u16* pH = gH + ((size_t)octc * 32 + col) * 8;
                        const u16* pL = gL + ((size_t)octc * 32 + col) * 8;
                        AH0[kt] = ldA(pH);  AH1[kt] = ldA(pH + 128);
                        AL0[kt] = ldA(pL);  AL1[kt] = ldA(pL + 128);
                    }
                    // (2) next-phase stage: flies during compute + barrier
                    stage_mogF(mW + (size_t)((ph + 1) % 5) * 1048576, jb, wdst, lane, wv);
                    // (3) MFMA
                    f32x4 a0 = {0.f, 0.f, 0.f, 0.f}, a1 = {0.f, 0.f, 0.f, 0.f};
#pragma unroll
                    for (int kt = 0; kt < 8; ++kt) {
                        int octc = wv * 32 + kt * 4 + kq4;
                        const float* wp = wsrc + octc * 128 + col * 8;
                        f32x4 w0 = *(const f32x4*)wp, w1 = *(const f32x4*)(wp + 4);
                        bf16x8 whi = mkfrag(pkhi(w0.x, w0.y), pkhi(w0.z, w0.w),
                                            pkhi(w1.x, w1.y), pkhi(w1.z, w1.w));
                        bf16x8 wlo = mkfrag(pklo(w0.x, w0.y), pklo(w0.z, w0.w),
                                            pklo(w1.x, w1.y), pklo(w1.z, w1.w));
                        a0 = __builtin_amdgcn_mfma_f32_16x16x32_bf16(AH0[kt], whi, a0, 0, 0, 0);
                        a0 = __builtin_amdgcn_mfma_f32_16x16x32_bf16(AL0[kt], whi, a0, 0, 0, 0);
                        a0 = __builtin_amdgcn_mfma_f32_16x16x32_bf16(AH0[kt], wlo, a0, 0, 0, 0);
                        a1 = __builtin_amdgcn_mfma_f32_16x16x32_bf16(AH1[kt], whi, a1, 0, 0, 0);
                        a1 = __builtin_amdgcn_mfma_f32_16x16x32_bf16(AL1[kt], whi, a1, 0, 0, 0);
                        a1 = __builtin_amdgcn_mfma_f32_16x16x32_bf16(AH1[kt], wlo, a1, 0, 0, 0);
                    }
                    // (4) cross-wave reduce + gate + publish
#pragma unroll
                    for (int mh = 0; mh < 2; ++mh) {
                        f32x4 av = mh ? a1 : a0;
#pragma unroll
                        for (int r = 0; r < 4; ++r)
                            red[wv][mh * 16 + kq4 * 4 + r][col] = av[r];
                    }
                    __syncthreads();
#pragma unroll
                    for (int uu = 0; uu < 2; ++uu) {
                        int u = tid + uu * 256;
                        int jj = u & 15, bb = u >> 4;
                        float sv = red[0][bb][jj] + red[1][bb][jj]
                                 + red[2][bb][jj] + red[3][bb][jj];
                        int d = jb + jj;
                        sv += mb_[ph * 1024 + d];
                        float gate = 2.0f * sigmoidf_(sv);
                        size_t pidx = ((size_t)(d >> 3) * 32 + bb) * 8 + (d & 7);
                        float val = gate * ldc4(srcF + pidx);
                        stc4(dF + pidx, val);
                        u32 uv = __float_as_uint(val);
                        stc2(dH + pidx, (u16)(uv >> 16));
                        float lov = val - __uint_as_float(uv & 0xffff0000u);
                        stc2(dL + pidx, (u16)(__float_as_uint(lov) >> 16));
                    }
                    arrA(A.bar, line);      // publish + drain own stage
                } else {
                    stage_mogF(mW + (size_t)((ph + 1) % 5) * 1048576, jb, wdst, lane, wv);
                    arrP(A.bar, line);
                }
                ++bcnt;
                bwait(A.bar, layer, master, false, bcnt);
                cur ^= 1;
            }
            // g6 (global slot barrier): mog idle since g5, passive
            arrP(A.bar, line);
            ++bcnt;
            bwait(A.bar, layer, master, true, bcnt);
        } else {
            // ---------- LSTM block ----------
            if (act) {
#pragma unroll
                for (int c = 0; c < 4; ++c)           // Whh c0..c3 fly through ph0-ph3
                    stage_l128(Whh, jb, c * 128, &wbuf[c][0], lane, wv);
            }
#pragma unroll
            for (int p = 0; p < 4; ++p) {             // b1..b4 (ends of ph0..ph3)
                arrP(A.bar, line);
                ++bcnt;
                bwait(A.bar, layer, false, false, bcnt);
            }
            // arrive at g5 BEFORE Whh compute: g5 gated only by mog ph4
            arrP(A.bar, line);
            ++bcnt;
            u32 g5t = bcnt;
            f32x4 acc[4][2];
#pragma unroll
            for (int rt = 0; rt < 4; ++rt) {
                acc[rt][0] = (f32x4){0.f, 0.f, 0.f, 0.f};
                acc[rt][1] = (f32x4){0.f, 0.f, 0.f, 0.f};
            }
            if (act) {
                for (int c = 0; c < 8; ++c) {         // Whh side (overlaps mog ph4)
                    bf16x8 fr[4];
                    l_acts(hmH, hmL, c, lane, wv, fr);
                    l_mfma(&wbuf[c & 3][0], fr, lane, wv, acc);
                    int cn = c + 4;
                    if (cn < 8) stage_l128(Whh, jb, cn * 128, &wbuf[cn & 3][0], lane, wv);
                    else        stage_l128(Wih, jb, (cn - 8) * 128, &wbuf[cn & 3][0], lane, wv);
                }
            }
            bwait(A.bar, layer, false, false, g5t);   // x ready
            if (act) {
                for (int c = 8; c < 16; ++c) {        // Wih side (global chunks 8..15)
                    bf16x8 fr[4];
                    l_acts(xH, xL, c - 8, lane, wv, fr);
                    l_mfma(&wbuf[c & 3][0], fr, lane, wv, acc);
                    int cn = c + 4;
                    if (cn < 16) stage_l128(Wih, jb, (cn - 8) * 128, &wbuf[cn & 3][0], lane, wv);
                }
                // cross-wave K reduction, gates, state update
                float gv[2][4];
#pragma unroll
                for (int gt = 0; gt < 4; ++gt) {
                    __syncthreads();
#pragma unroll
                    for (int mh = 0; mh < 2; ++mh) {
                        f32x4 av = acc[gt][mh];
#pragma unroll
                        for (int r = 0; r < 4; ++r)
                            red[wv][mh * 16 + kq4 * 4 + r][col] = av[r];
                    }
                    __syncthreads();
#pragma unroll
                    for (int uu = 0; uu < 2; ++uu) {
                        int u = tid + uu * 256;
                        gv[uu][gt] = red[0][u >> 4][u & 15] + red[1][u >> 4][u & 15]
                                   + red[2][u >> 4][u & 15] + red[3][u >> 4][u & 15];
                    }
                }
#pragma unroll
                for (int uu = 0; uu < 2; ++uu) {
                    int u = tid + uu * 256;
                    int cell = u & 15, bb = u >> 4;
                    int d = jb + cell;
                    float gi = gv[uu][0] + bih[d] + bhh[d];
                    float gf = gv[uu][1] + bih[1024 + d] + bhh[1024 + d];
                    float gg = gv[uu][2] + bih[2048 + d] + bhh[2048 + d];
                    float go = gv[uu][3] + bih[3072 + d] + bhh[3072 + d];
                    int cidx = d * 32 + bb;
                    float cn = sigmoidf_(gf) * cS[cidx] + sigmoidf_(gi) * tanhf_(gg);
                    cS[cidx] = cn;
                    float hn = sigmoidf_(go) * tanhf_(cn);
                    size_t pidx = ((size_t)(d >> 3) * 32 + bb) * 8 + (d & 7);
                    u32 uv = __float_as_uint(hn);
                    u16 hhi = (u16)(uv >> 16);
                    float lov = hn - __uint_as_float(uv & 0xffff0000u);
                    u16 hlo = (u16)(__float_as_uint(lov) >> 16);
                    stc4(hF + pidx, hn);
                    stc2(hH + pidx, hhi);
                    stc2(hL + pidx, hlo);
                    if (layer == 0) {
                        int wb = s & 1;
                        stc4(rFb + wb * 32768 + pidx, hn);
                        stc2(rHb + wb * 32768 + pidx, hhi);
                        stc2(rLb + wb * 32768 + pidx, hlo);
                    } else {
                        A.hs[(size_t)bb * 65536 + (size_t)t * 1024 + d] = hn;
                    }
                }
                arrA(A.bar, line);                    // g6: publish h (drain stores)
                ++bcnt;
            } else {
                arrP(A.bar, line);
                ++bcnt;
            }
            bwait(A.bar, layer, false, true, bcnt);   // global slot barrier
        }
    }
}

// ---------------- embedding gather into fp32 + hi/lo bf16 planes ----------------
__global__ __launch_bounds__(256) void gather_embed(const int* __restrict__ seq,
                                                    const float* __restrict__ emb,
                                                    float* __restrict__ XTF,
                                                    u16* __restrict__ XTH,
                                                    u16* __restrict__ XTL) {
    int t = blockIdx.x;
#pragma unroll 4
    for (int i = 0; i < 16; ++i) {
        int u = i * 256 + threadIdx.x;
        int oct = u >> 5, b = u & 31;
        int row = seq[b * 64 + t];
        const float* sp = emb + (size_t)row * 1024 + oct * 8;
        float4 f0 = *(const float4*)sp;
        float4 f1 = *(const float4*)(sp + 4);
        size_t base = (size_t)t * 32768 + ((size_t)oct * 32 + b) * 8;
        *(float4*)(XTF + base) = f0;
        *(float4*)(XTF + base + 4) = f1;
        u32x4 hi = {pkhi(f0.x, f0.y), pkhi(f0.z, f0.w), pkhi(f1.x, f1.y), pkhi(f1.z, f1.w)};
        u32x4 lo = {pklo(f0.x, f0.y), pklo(f0.z, f0.w), pklo(f1.x, f1.y), pklo(f1.z, f1.w)};
        *(u32x4*)(XTH + base) = hi;
        *(u32x4*)(XTL + base) = lo;
    }
}

// ---------------- fp32 -> bf16 (RNE, projection A) ----------------
__global__ __launch_bounds__(256) void f32_to_bf16(const float* __restrict__ in,
                                                   unsigned short* __restrict__ out, int n) {
    int i = (blockIdx.x * 256 + threadIdx.x) * 8;
    if (i + 7 < n) {
        float4 f0 = *(const float4*)(in + i);
        float4 f1 = *(const float4*)(in + i + 4);
        bf16x8 v;
        v[0] = (short)f2bf(f0.x); v[1] = (short)f2bf(f0.y);
        v[2] = (short)f2bf(f0.z); v[3] = (short)f2bf(f0.w);
        v[4] = (short)f2bf(f1.x); v[5] = (short)f2bf(f1.y);
        v[6] = (short)f2bf(f1.z); v[7] = (short)f2bf(f1.w);
        *(bf16x8*)(out + i) = v;
    }
}

// ---------------- output projection (bf16 MFMA, 128x128 tile) ----------------
__global__ __launch_bounds__(256) void out_proj(const unsigned short* __restrict__ hsb,
                                                const float* __restrict__ emb,
                                                const float* __restrict__ fcb,
                                                float* __restrict__ out) {
    __shared__ unsigned short Al[128 * 40];
    __shared__ unsigned short Bl[128 * 40];
    int tid = threadIdx.x;
    int n0 = blockIdx.x * 128;
    int m0 = blockIdx.y * 128;
    int wid = tid >> 6, l = tid & 63;
    int wm = wid >> 1, wn = wid & 1;
    int c16 = l & 15, kg = l >> 4;

    f32x4 acc[4][4];
#pragma unroll
    for (int i = 0; i < 4; i++)
#pragma unroll
        for (int j = 0; j < 4; j++) acc[i][j] = (f32x4){0.f, 0.f, 0.f, 0.f};

    for (int k0 = 0; k0 < 1024; k0 += 32) {
#pragma unroll
        for (int i = 0; i < 2; i++) {
            int id = i * 256 + tid;
            int r = id >> 2, ccc = id & 3;
            *(bf16x8*)&Al[r * 40 + ccc * 8] =
                *(const bf16x8*)(hsb + (size_t)(m0 + r) * 1024 + k0 + ccc * 8);
        }
#pragma unroll
        for (int i = 0; i < 2; i++) {
            int id = i * 256 + tid;
            int r = id >> 2, ccc = id & 3;
            const float* src = emb + (size_t)(n0 + r) * 1024 + k0 + ccc * 8;
            float4 f0 = *(const float4*)(src);
            float4 f1 = *(const float4*)(src + 4);
            bf16x8 v;
            v[0] = (short)f2bf(f0.x); v[1] = (short)f2bf(f0.y);
            v[2] = (short)f2bf(f0.z); v[3] = (short)f2bf(f0.w);
            v[4] = (short)f2bf(f1.x); v[5] = (short)f2bf(f1.y);
            v[6] = (short)f2bf(f1.z); v[7] = (short)f2bf(f1.w);
            *(bf16x8*)&Bl[r * 40 + ccc * 8] = v;
        }
        __syncthreads();

        bf16x8 afr[4], bfr[4];
#pragma unroll
        for (int i = 0; i < 4; i++)
            afr[i] = *(const bf16x8*)&Al[(wm * 64 + i * 16 + c16) * 40 + kg * 8];
#pragma unroll
        for (int j = 0; j < 4; j++)
            bfr[j] = *(const bf16x8*)&Bl[(wn * 64 + j * 16 + c16) * 40 + kg * 8];
#pragma unroll
        for (int i = 0; i < 4; i++)
#pragma unroll
            for (int j = 0; j < 4; j++)
                acc[i][j] = __builtin_amdgcn_mfma_f32_16x16x32_bf16(afr[i], bfr[j], acc[i][j], 0, 0, 0);
        __syncthreads();
    }

#pragma unroll
    for (int i = 0; i < 4; i++) {
        int row = m0 + wm * 64 + i * 16 + kg * 4;
#pragma unroll
        for (int j = 0; j < 4; j++) {
            int col = n0 + wn * 64 + j * 16 + c16;
            float fb = fcb[col];
#pragma unroll
            for (int r = 0; r < 4; r++)
                out[(size_t)(row + r) * 32000 + col] = acc[i][j][r] + fb;
        }
    }
}

// ---------------- host ----------------
extern "C" void kernel_launch(void* const* d_in, const int* in_sizes, int n_in,
                              void* d_out, int out_size, void* d_ws, size_t ws_size,
                              hipStream_t stream) {
    const int*   seq    = (const int*)d_in[0];
    const float* emb    = (const float*)d_in[2];
    const float* mog1_W = (const float*)d_in[3];
    const float* mog1_b = (const float*)d_in[4];
    const float* W_ih1  = (const float*)d_in[5];
    const float* W_hh1  = (const float*)d_in[6];
    const float* b_ih1  = (const float*)d_in[7];
    const float* b_hh1  = (const float*)d_in[8];
    const float* mog2_W = (const float*)d_in[9];
    const float* mog2_b = (const float*)d_in[10];
    const float* W_ih2  = (const float*)d_in[11];
    const float* W_hh2  = (const float*)d_in[12];
    const float* b_ih2  = (const float*)d_in[13];
    const float* b_hh2  = (const float*)d_in[14];
    const float* fc_b   = (const float*)d_in[15];

    char* ws = (char*)d_ws;
    float* XTF = (float*)ws;                                  // 8 MB
    u16*   XTH = (u16*)(ws + 8388608);                        // 4 MB
    u16*   XTL = (u16*)(ws + 12582912);                       // 4 MB
    float* stF = (float*)(ws + 16777216);                     // 1 MB
    u16*   stH = (u16*)(ws + 17825792);                       // 768 KB
    u32*   bar = (u32*)(ws + 18874368);                       // 16 KB
    unsigned short* hsb = (unsigned short*)(ws + 18890752);   // 4 MB

    float* out0 = (float*)d_out;
    float* hs   = out0 + 65536000LL;

    (void)hipMemsetAsync(stF, 0, 1835008, stream);
    (void)hipMemsetAsync(bar, 0, 16384, stream);

    gather_embed<<<64, 256, 0, stream>>>(seq, emb, XTF, XTH, XTL);

    RArgs a;
    a.m1W = mog1_W; a.m1b = mog1_b;
    a.Wih1 = W_ih1; a.Whh1 = W_hh1; a.bih1 = b_ih1; a.bhh1 = b_hh1;
    a.m2W = mog2_W; a.m2b = mog2_b;
    a.Wih2 = W_ih2; a.Whh2 = W_hh2; a.bih2 = b_ih2; a.bhh2 = b_hh2;
    a.XTF = XTF; a.XTH = XTH; a.XTL = XTL;
    a.stF = stF; a.stH = stH; a.hs = hs; a.bar = bar;

    reck<<<256, 256, 0, stream>>>(a);

    f32_to_bf16<<<1024, 256, 0, stream>>>(hs, hsb, 2097152);
    out_proj<<<dim3(250, 16), 256, 0, stream>>>(hsb, emb, fc_b, out0);
}